// Round 12
// baseline (767.079 us; speedup 1.0000x reference)
//
#include <hip/hip_runtime.h>

#define D 128
typedef unsigned long long u64;
typedef __attribute__((ext_vector_type(8))) short bf16x8;
typedef __attribute__((ext_vector_type(4))) float f32x4;

__device__ __forceinline__ unsigned short f2bf(float f){   // round-to-nearest-even
  unsigned int u = __float_as_uint(f);
  return (unsigned short)((u + 0x7FFFu + ((u >> 16) & 1u)) >> 16);
}
__device__ __forceinline__ float bf2f(unsigned short h){
  return __uint_as_float(((unsigned int)h) << 16);
}
// round-nearest split: hi = rn16(f), lo = rn16(f - hi)  -> |f - hi - lo| ~ 2^-18 |f|
__device__ __forceinline__ void cvt8(float4 a0, float4 a1, bf16x8 &hi, bf16x8 &lo){
  float f[8] = {a0.x,a0.y,a0.z,a0.w,a1.x,a1.y,a1.z,a1.w};
#pragma unroll
  for (int j=0;j<8;++j){
    unsigned short h = f2bf(f[j]);
    hi[j] = (short)h;
    lo[j] = (short)f2bf(f[j] - bf2f(h));
  }
}

// ---------------- graph prep ----------------

__global__ __launch_bounds__(256) void k_hist(const int* __restrict__ dstA, const int* __restrict__ dstB,
                                              int* __restrict__ deg, int N, int E){
  int e = blockIdx.x*256 + threadIdx.x;
  int y = blockIdx.y;
  const int* d = y ? dstB : dstA;
  if (e < E) atomicAdd(&deg[(u64)y*N + d[e]], 1);
}

__global__ __launch_bounds__(1024) void k_scan(const int* __restrict__ degA, int* __restrict__ offA,
                                               int* __restrict__ curA, int n){
  int y = blockIdx.y;
  const int* deg = degA + (u64)y*n;
  int* off = offA + (u64)y*(n+1);
  int* cur = curA + (u64)y*n;
  __shared__ int wsum[16];
  __shared__ int carry_sh;
  int t = threadIdx.x, lane = t & 63, wid = t >> 6;
  if (t == 0) carry_sh = 0;
  __syncthreads();
  const int TILE = 4096;
  for (int base = 0; base < n; base += TILE){
    int idx = base + t*4;
    int v0 = (idx+0 < n)? deg[idx+0] : 0;
    int v1 = (idx+1 < n)? deg[idx+1] : 0;
    int v2 = (idx+2 < n)? deg[idx+2] : 0;
    int v3 = (idx+3 < n)? deg[idx+3] : 0;
    int tsum = v0+v1+v2+v3;
    int sc = tsum;                       // inclusive wave scan
    for (int o=1;o<64;o<<=1){ int u = __shfl_up(sc,o); if (lane>=o) sc += u; }
    if (lane == 63) wsum[wid] = sc;
    __syncthreads();
    if (wid == 0 && lane < 16){
      int ws = wsum[lane];
      int s2 = ws;
      for (int o=1;o<16;o<<=1){ int u = __shfl_up(s2,o); if (lane>=o) s2 += u; }
      wsum[lane] = s2 - ws;              // exclusive wave offsets
    }
    __syncthreads();
    int excl = carry_sh + wsum[wid] + sc - tsum;
    int run = excl;
    if (idx+0 < n){ off[idx+0]=run; cur[idx+0]=run; run+=v0; }
    if (idx+1 < n){ off[idx+1]=run; cur[idx+1]=run; run+=v1; }
    if (idx+2 < n){ off[idx+2]=run; cur[idx+2]=run; run+=v2; }
    if (idx+3 < n){ off[idx+3]=run; cur[idx+3]=run; run+=v3; }
    __syncthreads();
    if (t == 1023) carry_sh = excl + tsum;
    __syncthreads();
  }
  if (t == 0) off[n] = carry_sh;
}

__global__ __launch_bounds__(256) void k_fill(const int* __restrict__ eiA, const int* __restrict__ eiB,
                                              int* __restrict__ cur, int* __restrict__ csr, int N, int E){
  int e = blockIdx.x*256 + threadIdx.x;
  int y = blockIdx.y;
  const int* ei = y ? eiB : eiA;
  if (e < E){
    int p = atomicAdd(&cur[(u64)y*N + ei[E + e]], 1);
    csr[(u64)y*E + p] = ei[e];
  }
}

// ---------------- xsum for layer 0 (deg-weighted column sums of initial x) ----------------

__global__ __launch_bounds__(256) void k_xsum0(const float* __restrict__ x0, const float* __restrict__ x1,
                                               const int* __restrict__ deg, float* __restrict__ xpart,
                                               int N, int RPB){
  int y = blockIdx.y;
  const float* x = y ? x1 : x0;
  const int* dg = deg + (u64)y*N;
  int sub = threadIdx.x >> 5, sl = threadIdx.x & 31;
  int r0 = blockIdx.x*RPB;
  int r1 = r0 + RPB; if (r1 > N) r1 = N;
  float4 a = make_float4(0.f,0.f,0.f,0.f);
  for (int r = r0 + sub; r < r1; r += 8){
    float d = (float)dg[r];
    if (d != 0.f){
      float4 xv = *(const float4*)(x + (u64)r*D + sl*4);
      a.x = fmaf(d, xv.x, a.x); a.y = fmaf(d, xv.y, a.y);
      a.z = fmaf(d, xv.z, a.z); a.w = fmaf(d, xv.w, a.w);
    }
  }
  __shared__ float sh[1024];
  *(float4*)(sh + sub*128 + sl*4) = a;
  __syncthreads();
  if (threadIdx.x < 128){
    float s = 0.f;
#pragma unroll
    for (int i=0;i<8;++i) s += sh[i*128 + threadIdx.x];
    xpart[((u64)y*gridDim.x + blockIdx.x)*128 + threadIdx.x] = s;
  }
}

// ---- stage A: coalesced f32 partials -> 32 f64 partial rows per type ----
__global__ __launch_bounds__(256) void k_redA(const float* __restrict__ xpart, double* __restrict__ xpd, int nblk){
  int y = blockIdx.y, b = blockIdx.x;        // grid (32, 2)
  int chunk = (nblk + 31)/32;
  int r0 = b*chunk, r1 = r0 + chunk; if (r1 > nblk) r1 = nblk;
  int col = threadIdx.x & 127, half = threadIdx.x >> 7;
  double acc = 0.0;
  for (int r = r0 + half; r < r1; r += 2)
    acc += (double)xpart[((u64)y*nblk + r)*128 + col];
  __shared__ double sh[256];
  sh[threadIdx.x] = acc;
  __syncthreads();
  if (half == 0) xpd[((u64)y*32 + b)*128 + col] = acc + sh[col + 128];
}

__global__ __launch_bounds__(256) void k_zred(const double* __restrict__ zpart, double* __restrict__ Z, int nblk){
  int y = blockIdx.x;
  double z = 0.0;
  for (int i = threadIdx.x; i < nblk; i += 256) z += zpart[(u64)y*nblk + i];
#pragma unroll
  for (int o=32;o;o>>=1) z += __shfl_xor(z, o);
  __shared__ double sh[4];
  if ((threadIdx.x & 63) == 0) sh[threadIdx.x >> 6] = z;
  __syncthreads();
  if (threadIdx.x == 0) Z[y] = sh[0]+sh[1]+sh[2]+sh[3];
}

// ---------------- weight packing (bf16 hi/lo split, MFMA-fragment order) ----------------
// fragment halfword index o for (k,col): ct=col>>4, ks=k>>5, lane=(col&15)|(((k>>3)&3)<<4), j=k&7

__global__ __launch_bounds__(256) void k_pack(const float* __restrict__ W0, int wstride,
                                              unsigned short* __restrict__ ph, unsigned short* __restrict__ pl){
  int o = blockIdx.x*256 + threadIdx.x;      // 0..16383
  int y = blockIdx.y;
  int j = o & 7, lane = (o>>3) & 63, ks = (o>>9) & 3, ct = o >> 11;
  int k = ks*32 + ((lane>>4)<<3) + j;
  int col = (ct<<4) + (lane&15);
  float wv = W0[(u64)y*wstride + k*128 + col];
  unsigned short h = f2bf(wv);
  ph[(u64)y*16384 + o] = h;
  pl[(u64)y*16384 + o] = f2bf(wv - bf2f(h));
}

// ---------------- merged per-layer prep: coef (blocks 0-1) | prepM (2-257) | pack Wv (258-385) ----------------

__global__ __launch_bounds__(256) void k_prep(const double* __restrict__ xpd, const float* __restrict__ qkv_w,
                                              const float* __restrict__ qkv_b, const float* __restrict__ rel_w,
                                              int L, int E, double* __restrict__ c, double* __restrict__ c0,
                                              unsigned short* __restrict__ MH, float* __restrict__ u1,
                                              float* __restrict__ b0, unsigned short* __restrict__ WvH,
                                              unsigned short* __restrict__ WvL){
  __shared__ double sh[128];
  __shared__ double xs[128];
  __shared__ float qrow[128];
  int b = blockIdx.x, t = threadIdx.x;
  if (b < 2){
    // ---- coef for src type tt (f64 logit chain) ----
    int tt = b;
    const float* Wk = qkv_w + (u64)((L*2 + (1-tt))*3 + 1)*D*D;
    const float* bk = qkv_b + (u64)((L*2 + (1-tt))*3 + 1)*D;
    const float* Wq = qkv_w + (u64)((L*2 + tt)*3 + 0)*D*D;
    const float* bq = qkv_b + (u64)((L*2 + tt)*3 + 0)*D;
    const float* rel = rel_w + (u64)(L*2 + tt)*D*D;
    const double* xp = xpd + (u64)(1-tt)*32*128;
    int j = t;
    if (j < 128){
      double a = 0.0;
      for (int b2=0;b2<32;++b2) a += xp[b2*128 + j];
      xs[j] = a;
    }
    __syncthreads();
    double ks = 0.0;
    if (j < 128){
      ks = (double)E * (double)bk[j];
      for (int d=0; d<128; ++d) ks += xs[d] * (double)Wk[d*128+j];
      sh[j] = ks;
    }
    __syncthreads();
    double tmp = 0.0;
    if (j < 128){
      for (int cc=0; cc<128; ++cc) tmp += (double)rel[j*128+cc] * sh[cc];
    }
    __syncthreads();
    if (j < 128) sh[j] = tmp;
    __syncthreads();
    if (j < 128){
      const double scale = 0.08838834764831843;  // 1/sqrt(128)
      double cv = 0.0;
      for (int k2=0;k2<128;++k2) cv += (double)Wq[j*128+k2] * sh[k2];
      c[tt*128 + j] = cv * scale;
      if (j == 0){
        double z = 0.0;
        for (int k2=0;k2<128;++k2) z += (double)bq[k2] * sh[k2];
        c0[tt] = z * scale;
      }
    }
  } else if (b < 258){
    // ---- prepM: M[a][:] for (y, a) ----
    int idx = b - 2;
    int y = idx >> 7, a = idx & 127;
    const float* Wq = qkv_w + (u64)((L*2 + y)*3 + 0)*D*D;
    const float* Wk = qkv_w + (u64)((L*2 + y)*3 + 1)*D*D;
    const float* bq = qkv_b + (u64)((L*2 + y)*3 + 0)*D;
    const float* bk = qkv_b + (u64)((L*2 + y)*3 + 1)*D;
    if (t < 128) qrow[t] = Wq[a*128+t];
    __syncthreads();
    if (t < 128){
      int bcol = t;
      const float* krow = Wk + bcol*128;
      float acc = 0.f;
      for (int j=0;j<128;++j) acc += qrow[j]*krow[j];
      int o = (bcol>>4)*2048 + (a>>5)*512 + (((bcol&15)|(((a>>3)&3)<<4)))*8 + (a&7);
      MH[(u64)y*16384 + o] = f2bf(acc);
      if (bcol == 0){
        float s1 = 0.f;
        for (int j=0;j<128;++j) s1 += Wq[a*128+j]*bk[j] + Wk[a*128+j]*bq[j];
        u1[y*D + a] = s1;
        if (a == 0){
          float z = 0.f;
          for (int j=0;j<128;++j) z += bq[j]*bk[j];
          b0[y] = z;
        }
      }
    }
  } else {
    // ---- pack Wv (both types) ----
    int lin = (b - 258)*256 + t;               // 0..32767
    int y = lin >> 14, o = lin & 16383;
    int j = o & 7, lane = (o>>3) & 63, ks = (o>>9) & 3, ct = o >> 11;
    int k = ks*32 + ((lane>>4)<<3) + j;
    int col = (ct<<4) + (lane&15);
    float wv = qkv_w[(u64)((L*2 + y)*3 + 2)*D*D + k*128 + col];
    unsigned short h = f2bf(wv);
    WvH[(u64)y*16384 + o] = h;
    WvL[(u64)y*16384 + o] = f2bf(wv - bf2f(h));
  }
}

// ---------------- fused quadform + v-projection MFMA kernel (single 32 KB staging buffer) ----------------

template<int VBF16>
__global__ __launch_bounds__(256,3) void k_mfqv(
    const float* __restrict__ x0, const float* __restrict__ x1,
    const unsigned short* __restrict__ MH,
    const unsigned short* __restrict__ WvH, const unsigned short* __restrict__ WvL,
    const float* __restrict__ bias_v, int bias_stride,
    const float* __restrict__ u1, const float* __restrict__ b0,
    const double* __restrict__ c, const double* __restrict__ c0,
    void* __restrict__ vout, float* __restrict__ lo_out,
    double* __restrict__ zpart, double* __restrict__ s, int N)
{
  __shared__ unsigned short shW[16384];      // 32 KB staging: M-hi -> Wv-hi -> Wv-lo
  __shared__ double csh[128];
  __shared__ float u1sh[128];
  __shared__ float bvsh[128];
  __shared__ double zsh[4];

  int y = blockIdx.y;
  int t = threadIdx.x;
  const float* x = y ? x1 : x0;

  {
    const uint4* gm = (const uint4*)(MH + (u64)y*16384);
    uint4* la = (uint4*)shW;
#pragma unroll
    for (int i=0;i<8;++i) la[t + i*256] = gm[t + i*256];
    if (t < 128){
      csh[t] = c[y*128 + t];
      u1sh[t] = u1[y*D + t];
      bvsh[t] = bias_v[(u64)y*bias_stride + t];
    }
  }
  __syncthreads();

  int w = t >> 6, lane = t & 63;
  int g = lane >> 4, cb = lane & 15;
  int strip0 = blockIdx.x*128 + w*32;
  int rA = strip0 + cb, rB = rA + 16;
  const float* xA = x + (u64)(rA < N ? rA : N-1)*D;
  const float* xB = x + (u64)(rB < N ? rB : N-1)*D;

  f32x4 accA[8], accB[8];
#pragma unroll
  for (int i=0;i<8;++i){
#pragma unroll
    for (int j=0;j<4;++j){ accA[i][j] = 0.f; accB[i][j] = 0.f; }
  }
  double saccA = 0.0, saccB = 0.0;
  bf16x8 fAh[4], fAl[4], fBh[4], fBl[4];

  const bf16x8* WF = (const bf16x8*)shW;

  // ---- phase 1: load fragments once, sdot (f64), M-GEMM (hi-only, 2 products) ----
#pragma unroll
  for (int ks=0; ks<4; ++ks){
    float4 a0  = *(const float4*)(xA + ks*32 + g*8);
    float4 a1  = *(const float4*)(xA + ks*32 + g*8 + 4);
    float4 bb0 = *(const float4*)(xB + ks*32 + g*8);
    float4 bb1 = *(const float4*)(xB + ks*32 + g*8 + 4);
    cvt8(a0, a1, fAh[ks], fAl[ks]);
    cvt8(bb0, bb1, fBh[ks], fBl[ks]);
    {
      const double* cp = csh + ks*32 + g*8;
      saccA += (double)a0.x*cp[0] + (double)a0.y*cp[1] + (double)a0.z*cp[2] + (double)a0.w*cp[3]
             + (double)a1.x*cp[4] + (double)a1.y*cp[5] + (double)a1.z*cp[6] + (double)a1.w*cp[7];
      saccB += (double)bb0.x*cp[0] + (double)bb0.y*cp[1] + (double)bb0.z*cp[2] + (double)bb0.w*cp[3]
             + (double)bb1.x*cp[4] + (double)bb1.y*cp[5] + (double)bb1.z*cp[6] + (double)bb1.w*cp[7];
    }
#pragma unroll
    for (int ct=0; ct<8; ++ct){
      bf16x8 mh = WF[(ct*4 + ks)*64 + lane];
      accA[ct] = __builtin_amdgcn_mfma_f32_16x16x32_bf16(mh, fAh[ks], accA[ct], 0, 0, 0);
      accA[ct] = __builtin_amdgcn_mfma_f32_16x16x32_bf16(mh, fAl[ks], accA[ct], 0, 0, 0);
      accB[ct] = __builtin_amdgcn_mfma_f32_16x16x32_bf16(mh, fBh[ks], accB[ct], 0, 0, 0);
      accB[ct] = __builtin_amdgcn_mfma_f32_16x16x32_bf16(mh, fBl[ks], accB[ct], 0, 0, 0);
    }
  }

  // ---- epilogue 1: l, Z partial, s ----
  {
    float dotA = 0.f, dotB = 0.f;
#pragma unroll
    for (int ct=0; ct<8; ++ct){
      float4 uv = ((const float4*)u1sh)[ct*4 + g];
      float4 xa = *(const float4*)(xA + ct*16 + g*4);
      float4 xb = *(const float4*)(xB + ct*16 + g*4);
      dotA += (accA[ct][0]+uv.x)*xa.x + (accA[ct][1]+uv.y)*xa.y
            + (accA[ct][2]+uv.z)*xa.z + (accA[ct][3]+uv.w)*xa.w;
      dotB += (accB[ct][0]+uv.x)*xb.x + (accB[ct][1]+uv.y)*xb.y
            + (accB[ct][2]+uv.z)*xb.z + (accB[ct][3]+uv.w)*xb.w;
    }
    dotA += __shfl_xor(dotA, 16); dotA += __shfl_xor(dotA, 32);
    dotB += __shfl_xor(dotB, 16); dotB += __shfl_xor(dotB, 32);
    double esum = 0.0;
    if (g == 0){
      float b0v = b0[y];
      if (rA < N){
        float lv = 0.08838834764831843f * (dotA + b0v);
        lo_out[(u64)y*N + rA] = lv; esum += (double)expf(lv);
      }
      if (rB < N){
        float lv = 0.08838834764831843f * (dotB + b0v);
        lo_out[(u64)y*N + rB] = lv; esum += (double)expf(lv);
      }
    }
#pragma unroll
    for (int o=1;o<64;o<<=1) esum += __shfl_xor(esum, o);
    if (lane == 0) zsh[w] = esum;

    saccA += __shfl_xor(saccA, 16); saccA += __shfl_xor(saccA, 32);
    saccB += __shfl_xor(saccB, 16); saccB += __shfl_xor(saccB, 32);
    if (g == 0){
      double cc0 = c0[y];
      if (rA < N) s[(u64)y*N + rA] = saccA + cc0;
      if (rB < N) s[(u64)y*N + rB] = saccB + cc0;
    }
  }
  __syncthreads();                           // phase-1 LDS reads done; zsh visible

  // ---- stage Wv-hi; write zpart ----
  {
    const uint4* gh = (const uint4*)(WvH + (u64)y*16384);
    uint4* la = (uint4*)shW;
#pragma unroll
    for (int i=0;i<8;++i) la[t + i*256] = gh[t + i*256];
  }
  if (t == 0) zpart[(u64)y*gridDim.x + blockIdx.x] = zsh[0]+zsh[1]+zsh[2]+zsh[3];
  __syncthreads();

  // ---- phase 2a: v-GEMM hi products ----
#pragma unroll
  for (int i=0;i<8;++i){
#pragma unroll
    for (int j=0;j<4;++j){ accA[i][j] = 0.f; accB[i][j] = 0.f; }
  }
#pragma unroll
  for (int ks=0; ks<4; ++ks){
#pragma unroll
    for (int ct=0; ct<8; ++ct){
      bf16x8 wh = WF[(ct*4 + ks)*64 + lane];
      accA[ct] = __builtin_amdgcn_mfma_f32_16x16x32_bf16(wh, fAh[ks], accA[ct], 0, 0, 0);
      accA[ct] = __builtin_amdgcn_mfma_f32_16x16x32_bf16(wh, fAl[ks], accA[ct], 0, 0, 0);
      accB[ct] = __builtin_amdgcn_mfma_f32_16x16x32_bf16(wh, fBh[ks], accB[ct], 0, 0, 0);
      accB[ct] = __builtin_amdgcn_mfma_f32_16x16x32_bf16(wh, fBl[ks], accB[ct], 0, 0, 0);
    }
  }

  // ---- phase 2b (f32-v only): Wv-lo x hi-fragments ----
  if (!VBF16){
    __syncthreads();
    {
      const uint4* gl = (const uint4*)(WvL + (u64)y*16384);
      uint4* la = (uint4*)shW;
#pragma unroll
      for (int i=0;i<8;++i) la[t + i*256] = gl[t + i*256];
    }
    __syncthreads();
#pragma unroll
    for (int ks=0; ks<4; ++ks){
#pragma unroll
      for (int ct=0; ct<8; ++ct){
        bf16x8 wl = WF[(ct*4 + ks)*64 + lane];
        accA[ct] = __builtin_amdgcn_mfma_f32_16x16x32_bf16(wl, fAh[ks], accA[ct], 0, 0, 0);
        accB[ct] = __builtin_amdgcn_mfma_f32_16x16x32_bf16(wl, fBh[ks], accB[ct], 0, 0, 0);
      }
    }
  }

  if (VBF16){
    unsigned short* outp = (unsigned short*)vout + (u64)y*N*D;
#pragma unroll
    for (int ct=0; ct<8; ++ct){
      float4 bv = ((const float4*)bvsh)[ct*4 + g];
      if (rA < N){
        ushort4 o;
        o.x = f2bf(accA[ct][0]+bv.x); o.y = f2bf(accA[ct][1]+bv.y);
        o.z = f2bf(accA[ct][2]+bv.z); o.w = f2bf(accA[ct][3]+bv.w);
        *(ushort4*)(outp + (u64)rA*D + ct*16 + g*4) = o;
      }
      if (rB < N){
        ushort4 o;
        o.x = f2bf(accB[ct][0]+bv.x); o.y = f2bf(accB[ct][1]+bv.y);
        o.z = f2bf(accB[ct][2]+bv.z); o.w = f2bf(accB[ct][3]+bv.w);
        *(ushort4*)(outp + (u64)rB*D + ct*16 + g*4) = o;
      }
    }
  } else {
    float* outp = (float*)vout + (u64)y*N*D;
#pragma unroll
    for (int ct=0; ct<8; ++ct){
      float4 bv = ((const float4*)bvsh)[ct*4 + g];
      if (rA < N){
        float4 o = make_float4(accA[ct][0]+bv.x, accA[ct][1]+bv.y, accA[ct][2]+bv.z, accA[ct][3]+bv.w);
        *(float4*)(outp + (u64)rA*D + ct*16 + g*4) = o;
      }
      if (rB < N){
        float4 o = make_float4(accB[ct][0]+bv.x, accB[ct][1]+bv.y, accB[ct][2]+bv.z, accB[ct][3]+bv.w);
        *(float4*)(outp + (u64)rB*D + ct*16 + g*4) = o;
      }
    }
  }
}

// ---------------- aggregation: 16 nodes per block (2 per 32-lane half) ----------------
// WX: write next-layer xsum partials. FUSE (L1): block does 16-row self-residual GEMM, writes FINAL f32.

template<int VBF16, int WX, int FUSE>
__global__ __launch_bounds__(256) void k_agg(const int* __restrict__ off, const int* __restrict__ csr,
                                             const double* __restrict__ s, const void* __restrict__ vv_,
                                             const float* __restrict__ l, const double* __restrict__ Z,
                                             float* __restrict__ out, float* __restrict__ xpart,
                                             const unsigned short* __restrict__ fuseW,
                                             const float* __restrict__ fuseB, int N, int E){
  __shared__ float shx[WX ? 1024 : 1];
  __shared__ unsigned short fh[FUSE?4:1][FUSE?64:1][8];
  __shared__ unsigned short fl[FUSE?4:1][FUSE?64:1][8];

  int t = threadIdx.x;
  int sl = t & 31;
  int hw = t >> 5;                           // 8 half-waves
  int hb = t & 32;
  int y = blockIdx.y;
  const int* offp = off + (u64)y*(N+1);
  const int* csrp = csr + (u64)y*E;
  const double* sp = s + (u64)(1-y)*N;       // logits live on src type = other type
  const float Zy = (float)Z[y];

  float4 xacc = make_float4(0.f,0.f,0.f,0.f);

  for (int nn = 0; nn < 2; ++nn){
    int n = blockIdx.x*16 + hw*2 + nn;
    if (n < N){
      int beg = offp[n], end = offp[n+1];
      int dg = end - beg;
      float ax=0.f, ay=0.f, az=0.f, aw=0.f;
      if (dg > 0){
        if (dg <= 32){
          bool act = sl < dg;
          int idx = csrp[beg + (act ? sl : 0)];
          double sv = act ? sp[idx] : -1e300;
          double m = sv;
#pragma unroll
          for (int o=16;o;o>>=1){ double u = __shfl_xor(m, o); m = u > m ? u : m; }
          float e = act ? expf((float)(sv - m)) : 0.f;
          float Zl = e;
#pragma unroll
          for (int o=16;o;o>>=1) Zl += __shfl_xor(Zl, o);
          float wgt = e / (Zl * (float)dg);
          for (int k=0;k<dg;++k){
            float wk = __shfl(wgt, hb + k);
            int sk = __shfl(idx, hb + k);
            if (VBF16){
              const unsigned short* vsrc = (const unsigned short*)vv_ + (u64)(1-y)*N*D;
              ushort4 vv = *(const ushort4*)(vsrc + (u64)sk*D + sl*4);
              ax = fmaf(wk, bf2f(vv.x), ax); ay = fmaf(wk, bf2f(vv.y), ay);
              az = fmaf(wk, bf2f(vv.z), az); aw = fmaf(wk, bf2f(vv.w), aw);
            } else {
              const float* vsrc = (const float*)vv_ + (u64)(1-y)*N*D;
              float4 vv = *(const float4*)(vsrc + (u64)sk*D + sl*4);
              ax = fmaf(wk, vv.x, ax); ay = fmaf(wk, vv.y, ay);
              az = fmaf(wk, vv.z, az); aw = fmaf(wk, vv.w, aw);
            }
          }
        } else {
          double m = -1e300;
          for (int e2=beg;e2<end;++e2){ double sv = sp[csrp[e2]]; m = sv > m ? sv : m; }
          float Zl = 0.f;
          for (int e2=beg;e2<end;++e2) Zl += expf((float)(sp[csrp[e2]] - m));
          float inv = 1.f / (Zl * (float)dg);
          for (int e2=beg;e2<end;++e2){
            int sk = csrp[e2];
            float wk = expf((float)(sp[sk] - m)) * inv;
            if (VBF16){
              const unsigned short* vsrc = (const unsigned short*)vv_ + (u64)(1-y)*N*D;
              ushort4 vv = *(const ushort4*)(vsrc + (u64)sk*D + sl*4);
              ax = fmaf(wk, bf2f(vv.x), ax); ay = fmaf(wk, bf2f(vv.y), ay);
              az = fmaf(wk, bf2f(vv.z), az); aw = fmaf(wk, bf2f(vv.w), aw);
            } else {
              const float* vsrc = (const float*)vv_ + (u64)(1-y)*N*D;
              float4 vv = *(const float4*)(vsrc + (u64)sk*D + sl*4);
              ax = fmaf(wk, vv.x, ax); ay = fmaf(wk, vv.y, ay);
              az = fmaf(wk, vv.z, az); aw = fmaf(wk, vv.w, aw);
            }
          }
        }
      }
      float a = expf(l[(u64)y*N + n]) / Zy;
      if (VBF16){
        const unsigned short* vself = (const unsigned short*)vv_ + (u64)y*N*D;
        ushort4 vs = *(const ushort4*)(vself + (u64)n*D + sl*4);
        ax = fmaf(a, bf2f(vs.x), ax); ay = fmaf(a, bf2f(vs.y), ay);
        az = fmaf(a, bf2f(vs.z), az); aw = fmaf(a, bf2f(vs.w), aw);
      } else {
        const float* vself = (const float*)vv_ + (u64)y*N*D;
        float4 vs = *(const float4*)(vself + (u64)n*D + sl*4);
        ax = fmaf(a, vs.x, ax); ay = fmaf(a, vs.y, ay);
        az = fmaf(a, vs.z, az); aw = fmaf(a, vs.w, aw);
      }
      if (FUSE){
        // write row (slot r) into MFMA B-fragment tables, bf16 hi/lo
        int r = hw*2 + nn;
        int ks = sl >> 3, g2 = (sl >> 1) & 3, j0 = (sl & 1)*4;
        ushort4 h, lo4;
        h.x = f2bf(ax); h.y = f2bf(ay); h.z = f2bf(az); h.w = f2bf(aw);
        lo4.x = f2bf(ax - bf2f(h.x)); lo4.y = f2bf(ay - bf2f(h.y));
        lo4.z = f2bf(az - bf2f(h.z)); lo4.w = f2bf(aw - bf2f(h.w));
        *(ushort4*)&fh[ks][r + 16*g2][j0] = h;
        *(ushort4*)&fl[ks][r + 16*g2][j0] = lo4;
      } else {
        *(float4*)(out + (u64)y*N*D + (u64)n*D + sl*4) = make_float4(ax, ay, az, aw);
        if (WX){
          float df = (float)dg;
          xacc.x = fmaf(df, ax, xacc.x); xacc.y = fmaf(df, ay, xacc.y);
          xacc.z = fmaf(df, az, xacc.z); xacc.w = fmaf(df, aw, xacc.w);
        }
      }
    }
  }
  if (WX){
    __syncthreads();
    *(float4*)(shx + hw*128 + sl*4) = xacc;
    __syncthreads();
    if (t < 128){
      float ssum = 0.f;
#pragma unroll
      for (int i=0;i<8;++i) ssum += shx[i*128 + t];
      xpart[((u64)y*gridDim.x + blockIdx.x)*128 + t] = ssum;
    }
  }
  if (FUSE){
    __syncthreads();
    // 16-row self-residual GEMM: final = gathered @ Wself (2-prod) + b + gathered
    const unsigned short* SHp = fuseW + (u64)y*16384;
    const float* bsp = fuseB + y*D;
    float* outp = out + (u64)y*N*D;
    int wv = t >> 6, lane = t & 63;
    int rloc = lane & 15, gq = lane >> 4;
    int n2 = blockIdx.x*16 + rloc;
#pragma unroll
    for (int cc2=0; cc2<2; ++cc2){
      int ct = wv*2 + cc2;
      f32x4 acc;
      acc[0]=0.f; acc[1]=0.f; acc[2]=0.f; acc[3]=0.f;
#pragma unroll
      for (int ks=0; ks<4; ++ks){
        bf16x8 wh = *(const bf16x8*)(SHp + ((u64)(ct*4+ks)*64 + lane)*8);
        bf16x8 xh = *(const bf16x8*)&fh[ks][lane][0];
        bf16x8 xl = *(const bf16x8*)&fl[ks][lane][0];
        acc = __builtin_amdgcn_mfma_f32_16x16x32_bf16(wh, xh, acc, 0, 0, 0);
        acc = __builtin_amdgcn_mfma_f32_16x16x32_bf16(wh, xl, acc, 0, 0, 0);
      }
      if (n2 < N){
        int col0 = ct*16 + gq*4;
        int ks2 = col0 >> 5, g22 = (col0 >> 3) & 3, j02 = col0 & 7;
        ushort4 rh = *(const ushort4*)&fh[ks2][rloc + 16*g22][j02];
        ushort4 rl = *(const ushort4*)&fl[ks2][rloc + 16*g22][j02];
        float4 bv = *(const float4*)(bsp + col0);
        float4 o;
        o.x = acc[0] + bv.x + bf2f(rh.x) + bf2f(rl.x);
        o.y = acc[1] + bv.y + bf2f(rh.y) + bf2f(rl.y);
        o.z = acc[2] + bv.z + bf2f(rh.z) + bf2f(rl.z);
        o.w = acc[3] + bv.w + bf2f(rh.w) + bf2f(rl.w);
        *(float4*)(outp + (u64)n2*D + col0) = o;
      }
    }
  }
}

// ---------------- launch ----------------

extern "C" void kernel_launch(void* const* d_in, const int* in_sizes, int n_in,
                              void* d_out, int out_size, void* d_ws, size_t ws_size,
                              hipStream_t stream){
  const float* x_user = (const float*)d_in[0];
  const float* x_item = (const float*)d_in[1];
  const int*   ei_u2i = (const int*)d_in[2];   // [2,E]: row0 src(user), row1 dst(item)
  const int*   ei_i2u = (const int*)d_in[3];   // [2,E]: row0 src(item), row1 dst(user)
  const float* qkv_w  = (const float*)d_in[4]; // [2,2,3,D,D]
  const float* qkv_b  = (const float*)d_in[5]; // [2,2,3,D]
  const float* rel_w  = (const float*)d_in[6]; // [2,2,D,D]
  const float* self_w = (const float*)d_in[7]; // [2,D,D]
  const float* self_b = (const float*)d_in[8]; // [2,D]

  const int N = in_sizes[0] / D;
  const int E = in_sizes[2] / 2;
  float* outU = (float*)d_out;                 // [2][N][D] contiguous (user then item)

  const int nblk = (N + 127)/128;
  const int RPB  = 160;
  const int NB0  = (N + RPB - 1)/RPB;
  const int gAgg = (N + 15)/16;
  const int maxPart = (gAgg > NB0 ? gAgg : NB0);

  char* p = (char*)d_ws;
  auto alloc = [&](size_t bytes)->char*{ char* r = p; p += (bytes + 255)/256*256; return r; };
  float*  v    = (float*) alloc((u64)2*N*D*4);           // f32 for L=0; aliased bf16 for L=1
  double* s    = (double*)alloc((u64)2*N*8);
  float*  l    = (float*) alloc((u64)2*N*4);
  int*    deg  = (int*)   alloc((u64)2*N*4);
  int*    off  = (int*)   alloc((u64)2*(N+1)*4);
  int*    cur  = (int*)   alloc((u64)2*N*4);
  int*    csr  = (int*)   alloc((u64)2*E*4);
  unsigned short* WvH = (unsigned short*)alloc(2*16384*2);
  unsigned short* WvL = (unsigned short*)alloc(2*16384*2);
  unsigned short* MH  = (unsigned short*)alloc(2*16384*2);
  unsigned short* SH  = (unsigned short*)alloc(2*16384*2);
  unsigned short* SL  = (unsigned short*)alloc(2*16384*2);
  float*  u1   = (float*) alloc(2*D*4);
  float*  b0   = (float*) alloc(256);
  double* zpart= (double*)alloc((u64)2*nblk*8);
  float*  xpart= (float*) alloc((u64)2*maxPart*128*4);
  double* xpd  = (double*)alloc((u64)2*32*128*8);
  double* Z    = (double*)alloc(256);
  double* c    = (double*)alloc(2*128*8);
  double* c0   = (double*)alloc(256);

  const int gE = (E + 255)/256;

  // ---- graph prep (layer-invariant): y=0 -> dst=user (ei_i2u), y=1 -> dst=item (ei_u2i)
  hipMemsetAsync(deg, 0, (u64)2*N*4, stream);
  k_hist<<<dim3(gE,2),256,0,stream>>>(ei_i2u + E, ei_u2i + E, deg, N, E);
  k_scan<<<dim3(1,2),1024,0,stream>>>(deg, off, cur, N);
  k_fill<<<dim3(gE,2),256,0,stream>>>(ei_i2u, ei_u2i, cur, csr, N, E);
  k_pack<<<dim3(64,2),256,0,stream>>>(self_w, D*D, SH, SL);

  // ---- layer-0 xsum from initial features
  k_xsum0<<<dim3(NB0,2),256,0,stream>>>(x_user, x_item, deg, xpart, N, RPB);
  k_redA<<<dim3(32,2),256,0,stream>>>(xpart, xpd, NB0);

  for (int L=0; L<2; ++L){
    const float* xu = L ? outU : x_user;
    const float* xi = L ? (outU + (u64)N*D) : x_item;
    k_prep<<<386,256,0,stream>>>(xpd, qkv_w, qkv_b, rel_w, L, E, c, c0, MH, u1, b0, WvH, WvL);
    if (L == 0){
      k_mfqv<0><<<dim3(nblk,2),256,0,stream>>>(xu, xi, MH, WvH, WvL, qkv_b + (u64)(L*6+2)*D, 3*D,
                                               u1, b0, c, c0, (void*)v, l, zpart, s, N);
      k_zred<<<2,256,0,stream>>>(zpart, Z, nblk);
      k_agg<0,1,0><<<dim3(gAgg,2),256,0,stream>>>(off, csr, s, (const void*)v, l, Z,
                                                  outU, xpart, nullptr, nullptr, N, E);
      k_redA<<<dim3(32,2),256,0,stream>>>(xpart, xpd, gAgg);
    } else {
      k_mfqv<1><<<dim3(nblk,2),256,0,stream>>>(xu, xi, MH, WvH, WvL, qkv_b + (u64)(L*6+2)*D, 3*D,
                                               u1, b0, c, c0, (void*)v, l, zpart, s, N);
      k_zred<<<2,256,0,stream>>>(zpart, Z, nblk);
      k_agg<1,0,1><<<dim3(gAgg,2),256,0,stream>>>(off, csr, s, (const void*)v, l, Z,
                                                  outU, xpart, SH, self_b, N, E);
    }
  }
}

// Round 13
// 680.684 us; speedup vs baseline: 1.1269x; 1.1269x over previous
//
#include <hip/hip_runtime.h>

#define D 128
typedef unsigned long long u64;
typedef __attribute__((ext_vector_type(8))) short bf16x8;
typedef __attribute__((ext_vector_type(4))) float f32x4;

__device__ __forceinline__ unsigned short f2bf(float f){   // round-to-nearest-even
  unsigned int u = __float_as_uint(f);
  return (unsigned short)((u + 0x7FFFu + ((u >> 16) & 1u)) >> 16);
}
__device__ __forceinline__ float bf2f(unsigned short h){
  return __uint_as_float(((unsigned int)h) << 16);
}
// round-nearest split: hi = rn16(f), lo = rn16(f - hi)  -> |f - hi - lo| ~ 2^-18 |f|
__device__ __forceinline__ void cvt8(float4 a0, float4 a1, bf16x8 &hi, bf16x8 &lo){
  float f[8] = {a0.x,a0.y,a0.z,a0.w,a1.x,a1.y,a1.z,a1.w};
#pragma unroll
  for (int j=0;j<8;++j){
    unsigned short h = f2bf(f[j]);
    hi[j] = (short)h;
    lo[j] = (short)f2bf(f[j] - bf2f(h));
  }
}

// ---------------- graph prep ----------------

__global__ __launch_bounds__(256) void k_hist(const int* __restrict__ dstA, const int* __restrict__ dstB,
                                              int* __restrict__ deg, int N, int E){
  int e = blockIdx.x*256 + threadIdx.x;
  int y = blockIdx.y;
  const int* d = y ? dstB : dstA;
  if (e < E) atomicAdd(&deg[(u64)y*N + d[e]], 1);
}

#define SCB 4096
__global__ __launch_bounds__(256) void k_scanA(const int* __restrict__ deg, int* __restrict__ bsum,
                                               int n, int nsb){
  int y = blockIdx.y, b = blockIdx.x;
  const int* d = deg + (u64)y*n;
  int i0 = b*SCB, i1 = i0 + SCB; if (i1 > n) i1 = n;
  int t = threadIdx.x;
  int a = 0;
  for (int i = i0 + t; i < i1; i += 256) a += d[i];
#pragma unroll
  for (int o=32;o;o>>=1) a += __shfl_xor(a, o);
  __shared__ int sh[4];
  if ((t & 63) == 0) sh[t >> 6] = a;
  __syncthreads();
  if (t == 0) bsum[y*nsb + b] = sh[0]+sh[1]+sh[2]+sh[3];
}

__global__ __launch_bounds__(256) void k_scanC(const int* __restrict__ deg, const int* __restrict__ bsum,
                                               int* __restrict__ off, int* __restrict__ cur,
                                               int n, int nsb, int E){
  int y = blockIdx.y, b = blockIdx.x;
  const int* d = deg + (u64)y*n;
  int* offp = off + (u64)y*(n+1);
  int* curp = cur + (u64)y*n;
  int t = threadIdx.x, lane = t & 63, wid = t >> 6;
  __shared__ int base_sh;
  __shared__ int wsum[4];
  if (t == 0){
    int base = 0;
    for (int i=0;i<b;++i) base += bsum[y*nsb + i];
    base_sh = base;
    if (b == 0) offp[n] = E;               // total degree == E exactly
  }
  __syncthreads();
  int idx = b*SCB + t*16;
  int v[16]; int tsum = 0;
#pragma unroll
  for (int j=0;j<16;++j){
    int ii = idx + j;
    v[j] = (ii < n) ? d[ii] : 0;
    tsum += v[j];
  }
  int sc = tsum;                           // inclusive wave scan
#pragma unroll
  for (int o=1;o<64;o<<=1){ int u = __shfl_up(sc, o); if (lane >= o) sc += u; }
  if (lane == 63) wsum[wid] = sc;
  __syncthreads();
  int wbase = 0;
  for (int i=0;i<wid;++i) wbase += wsum[i];
  int run = base_sh + wbase + sc - tsum;
#pragma unroll
  for (int j=0;j<16;++j){
    int ii = idx + j;
    if (ii < n){ offp[ii] = run; curp[ii] = run; run += v[j]; }
  }
}

__global__ __launch_bounds__(256) void k_fill(const int* __restrict__ eiA, const int* __restrict__ eiB,
                                              int* __restrict__ cur, int* __restrict__ csr, int N, int E){
  int e = blockIdx.x*256 + threadIdx.x;
  int y = blockIdx.y;
  const int* ei = y ? eiB : eiA;
  if (e < E){
    int p = atomicAdd(&cur[(u64)y*N + ei[E + e]], 1);
    csr[(u64)y*E + p] = ei[e];
  }
}

// ---------------- xsum for layer 0 (deg-weighted column sums of initial x) ----------------

__global__ __launch_bounds__(256) void k_xsum0(const float* __restrict__ x0, const float* __restrict__ x1,
                                               const int* __restrict__ deg, float* __restrict__ xpart,
                                               int N, int RPB){
  int y = blockIdx.y;
  const float* x = y ? x1 : x0;
  const int* dg = deg + (u64)y*N;
  int sub = threadIdx.x >> 5, sl = threadIdx.x & 31;
  int r0 = blockIdx.x*RPB;
  int r1 = r0 + RPB; if (r1 > N) r1 = N;
  float4 a = make_float4(0.f,0.f,0.f,0.f);
  for (int r = r0 + sub; r < r1; r += 8){
    float d = (float)dg[r];
    if (d != 0.f){
      float4 xv = *(const float4*)(x + (u64)r*D + sl*4);
      a.x = fmaf(d, xv.x, a.x); a.y = fmaf(d, xv.y, a.y);
      a.z = fmaf(d, xv.z, a.z); a.w = fmaf(d, xv.w, a.w);
    }
  }
  __shared__ float sh[1024];
  *(float4*)(sh + sub*128 + sl*4) = a;
  __syncthreads();
  if (threadIdx.x < 128){
    float s = 0.f;
#pragma unroll
    for (int i=0;i<8;++i) s += sh[i*128 + threadIdx.x];
    xpart[((u64)y*gridDim.x + blockIdx.x)*128 + threadIdx.x] = s;
  }
}

// ---- stage A: coalesced f32 partials -> 32 f64 partial rows per type ----
__global__ __launch_bounds__(256) void k_redA(const float* __restrict__ xpart, double* __restrict__ xpd, int nblk){
  int y = blockIdx.y, b = blockIdx.x;        // grid (32, 2)
  int chunk = (nblk + 31)/32;
  int r0 = b*chunk, r1 = r0 + chunk; if (r1 > nblk) r1 = nblk;
  int col = threadIdx.x & 127, half = threadIdx.x >> 7;
  double acc = 0.0;
  for (int r = r0 + half; r < r1; r += 2)
    acc += (double)xpart[((u64)y*nblk + r)*128 + col];
  __shared__ double sh[256];
  sh[threadIdx.x] = acc;
  __syncthreads();
  if (half == 0) xpd[((u64)y*32 + b)*128 + col] = acc + sh[col + 128];
}

__global__ __launch_bounds__(256) void k_zred(const double* __restrict__ zpart, double* __restrict__ Z, int nblk){
  int y = blockIdx.x;
  double z = 0.0;
  for (int i = threadIdx.x; i < nblk; i += 256) z += zpart[(u64)y*nblk + i];
#pragma unroll
  for (int o=32;o;o>>=1) z += __shfl_xor(z, o);
  __shared__ double sh[4];
  if ((threadIdx.x & 63) == 0) sh[threadIdx.x >> 6] = z;
  __syncthreads();
  if (threadIdx.x == 0) Z[y] = sh[0]+sh[1]+sh[2]+sh[3];
}

// ---------------- weight packing (bf16 hi/lo split, MFMA-fragment order) ----------------
// fragment halfword index o for (k,col): ct=col>>4, ks=k>>5, lane=(col&15)|(((k>>3)&3)<<4), j=k&7

__global__ __launch_bounds__(256) void k_pack(const float* __restrict__ W0, int wstride,
                                              unsigned short* __restrict__ ph, unsigned short* __restrict__ pl){
  int o = blockIdx.x*256 + threadIdx.x;      // 0..16383
  int y = blockIdx.y;
  int j = o & 7, lane = (o>>3) & 63, ks = (o>>9) & 3, ct = o >> 11;
  int k = ks*32 + ((lane>>4)<<3) + j;
  int col = (ct<<4) + (lane&15);
  float wv = W0[(u64)y*wstride + k*128 + col];
  unsigned short h = f2bf(wv);
  ph[(u64)y*16384 + o] = h;
  pl[(u64)y*16384 + o] = f2bf(wv - bf2f(h));
}

// ---------------- merged per-layer prep: coef (blocks 0-1) | prepM (2-257) | pack Wv (258-385) ----------------

__global__ __launch_bounds__(256) void k_prep(const double* __restrict__ xpd, const float* __restrict__ qkv_w,
                                              const float* __restrict__ qkv_b, const float* __restrict__ rel_w,
                                              int L, int E, double* __restrict__ c, double* __restrict__ c0,
                                              unsigned short* __restrict__ MH, float* __restrict__ u1,
                                              float* __restrict__ b0, unsigned short* __restrict__ WvH,
                                              unsigned short* __restrict__ WvL){
  __shared__ double sh[128];
  __shared__ double xs[128];
  __shared__ float qrow[128];
  int b = blockIdx.x, t = threadIdx.x;
  if (b < 2){
    // ---- coef for src type tt (f64 logit chain) ----
    int tt = b;
    const float* Wk = qkv_w + (u64)((L*2 + (1-tt))*3 + 1)*D*D;
    const float* bk = qkv_b + (u64)((L*2 + (1-tt))*3 + 1)*D;
    const float* Wq = qkv_w + (u64)((L*2 + tt)*3 + 0)*D*D;
    const float* bq = qkv_b + (u64)((L*2 + tt)*3 + 0)*D;
    const float* rel = rel_w + (u64)(L*2 + tt)*D*D;
    const double* xp = xpd + (u64)(1-tt)*32*128;
    int j = t;
    if (j < 128){
      double a = 0.0;
      for (int b2=0;b2<32;++b2) a += xp[b2*128 + j];
      xs[j] = a;
    }
    __syncthreads();
    double ks = 0.0;
    if (j < 128){
      ks = (double)E * (double)bk[j];
      for (int d=0; d<128; ++d) ks += xs[d] * (double)Wk[d*128+j];
      sh[j] = ks;
    }
    __syncthreads();
    double tmp = 0.0;
    if (j < 128){
      for (int cc=0; cc<128; ++cc) tmp += (double)rel[j*128+cc] * sh[cc];
    }
    __syncthreads();
    if (j < 128) sh[j] = tmp;
    __syncthreads();
    if (j < 128){
      const double scale = 0.08838834764831843;  // 1/sqrt(128)
      double cv = 0.0;
      for (int k2=0;k2<128;++k2) cv += (double)Wq[j*128+k2] * sh[k2];
      c[tt*128 + j] = cv * scale;
      if (j == 0){
        double z = 0.0;
        for (int k2=0;k2<128;++k2) z += (double)bq[k2] * sh[k2];
        c0[tt] = z * scale;
      }
    }
  } else if (b < 258){
    // ---- prepM: M[a][:] for (y, a) ----
    int idx = b - 2;
    int y = idx >> 7, a = idx & 127;
    const float* Wq = qkv_w + (u64)((L*2 + y)*3 + 0)*D*D;
    const float* Wk = qkv_w + (u64)((L*2 + y)*3 + 1)*D*D;
    const float* bq = qkv_b + (u64)((L*2 + y)*3 + 0)*D;
    const float* bk = qkv_b + (u64)((L*2 + y)*3 + 1)*D;
    if (t < 128) qrow[t] = Wq[a*128+t];
    __syncthreads();
    if (t < 128){
      int bcol = t;
      const float* krow = Wk + bcol*128;
      float acc = 0.f;
      for (int j=0;j<128;++j) acc += qrow[j]*krow[j];
      int o = (bcol>>4)*2048 + (a>>5)*512 + (((bcol&15)|(((a>>3)&3)<<4)))*8 + (a&7);
      MH[(u64)y*16384 + o] = f2bf(acc);
      if (bcol == 0){
        float s1 = 0.f;
        for (int j=0;j<128;++j) s1 += Wq[a*128+j]*bk[j] + Wk[a*128+j]*bq[j];
        u1[y*D + a] = s1;
        if (a == 0){
          float z = 0.f;
          for (int j=0;j<128;++j) z += bq[j]*bk[j];
          b0[y] = z;
        }
      }
    }
  } else {
    // ---- pack Wv (both types) ----
    int lin = (b - 258)*256 + t;               // 0..32767
    int y = lin >> 14, o = lin & 16383;
    int j = o & 7, lane = (o>>3) & 63, ks = (o>>9) & 3, ct = o >> 11;
    int k = ks*32 + ((lane>>4)<<3) + j;
    int col = (ct<<4) + (lane&15);
    float wv = qkv_w[(u64)((L*2 + y)*3 + 2)*D*D + k*128 + col];
    unsigned short h = f2bf(wv);
    WvH[(u64)y*16384 + o] = h;
    WvL[(u64)y*16384 + o] = f2bf(wv - bf2f(h));
  }
}

// ---------------- fused quadform + v-projection MFMA kernel (single 32 KB staging buffer) ----------------

template<int VBF16>
__global__ __launch_bounds__(256,3) void k_mfqv(
    const float* __restrict__ x0, const float* __restrict__ x1,
    const unsigned short* __restrict__ MH,
    const unsigned short* __restrict__ WvH, const unsigned short* __restrict__ WvL,
    const float* __restrict__ bias_v, int bias_stride,
    const float* __restrict__ u1, const float* __restrict__ b0,
    const double* __restrict__ c, const double* __restrict__ c0,
    void* __restrict__ vout, float* __restrict__ lo_out,
    double* __restrict__ zpart, double* __restrict__ s, int N)
{
  __shared__ unsigned short shW[16384];      // 32 KB staging: M-hi -> Wv-hi -> Wv-lo
  __shared__ double csh[128];
  __shared__ float u1sh[128];
  __shared__ float bvsh[128];
  __shared__ double zsh[4];

  int y = blockIdx.y;
  int t = threadIdx.x;
  const float* x = y ? x1 : x0;

  {
    const uint4* gm = (const uint4*)(MH + (u64)y*16384);
    uint4* la = (uint4*)shW;
#pragma unroll
    for (int i=0;i<8;++i) la[t + i*256] = gm[t + i*256];
    if (t < 128){
      csh[t] = c[y*128 + t];
      u1sh[t] = u1[y*D + t];
      bvsh[t] = bias_v[(u64)y*bias_stride + t];
    }
  }
  __syncthreads();

  int w = t >> 6, lane = t & 63;
  int g = lane >> 4, cb = lane & 15;
  int strip0 = blockIdx.x*128 + w*32;
  int rA = strip0 + cb, rB = rA + 16;
  const float* xA = x + (u64)(rA < N ? rA : N-1)*D;
  const float* xB = x + (u64)(rB < N ? rB : N-1)*D;

  f32x4 accA[8], accB[8];
#pragma unroll
  for (int i=0;i<8;++i){
#pragma unroll
    for (int j=0;j<4;++j){ accA[i][j] = 0.f; accB[i][j] = 0.f; }
  }
  double saccA = 0.0, saccB = 0.0;
  bf16x8 fAh[4], fAl[4], fBh[4], fBl[4];

  const bf16x8* WF = (const bf16x8*)shW;

  // ---- phase 1: load fragments once, sdot (f64), M-GEMM (hi-only, 2 products) ----
#pragma unroll
  for (int ks=0; ks<4; ++ks){
    float4 a0  = *(const float4*)(xA + ks*32 + g*8);
    float4 a1  = *(const float4*)(xA + ks*32 + g*8 + 4);
    float4 bb0 = *(const float4*)(xB + ks*32 + g*8);
    float4 bb1 = *(const float4*)(xB + ks*32 + g*8 + 4);
    cvt8(a0, a1, fAh[ks], fAl[ks]);
    cvt8(bb0, bb1, fBh[ks], fBl[ks]);
    {
      const double* cp = csh + ks*32 + g*8;
      saccA += (double)a0.x*cp[0] + (double)a0.y*cp[1] + (double)a0.z*cp[2] + (double)a0.w*cp[3]
             + (double)a1.x*cp[4] + (double)a1.y*cp[5] + (double)a1.z*cp[6] + (double)a1.w*cp[7];
      saccB += (double)bb0.x*cp[0] + (double)bb0.y*cp[1] + (double)bb0.z*cp[2] + (double)bb0.w*cp[3]
             + (double)bb1.x*cp[4] + (double)bb1.y*cp[5] + (double)bb1.z*cp[6] + (double)bb1.w*cp[7];
    }
#pragma unroll
    for (int ct=0; ct<8; ++ct){
      bf16x8 mh = WF[(ct*4 + ks)*64 + lane];
      accA[ct] = __builtin_amdgcn_mfma_f32_16x16x32_bf16(mh, fAh[ks], accA[ct], 0, 0, 0);
      accA[ct] = __builtin_amdgcn_mfma_f32_16x16x32_bf16(mh, fAl[ks], accA[ct], 0, 0, 0);
      accB[ct] = __builtin_amdgcn_mfma_f32_16x16x32_bf16(mh, fBh[ks], accB[ct], 0, 0, 0);
      accB[ct] = __builtin_amdgcn_mfma_f32_16x16x32_bf16(mh, fBl[ks], accB[ct], 0, 0, 0);
    }
  }

  // ---- epilogue 1: l, Z partial, s ----
  {
    float dotA = 0.f, dotB = 0.f;
#pragma unroll
    for (int ct=0; ct<8; ++ct){
      float4 uv = ((const float4*)u1sh)[ct*4 + g];
      float4 xa = *(const float4*)(xA + ct*16 + g*4);
      float4 xb = *(const float4*)(xB + ct*16 + g*4);
      dotA += (accA[ct][0]+uv.x)*xa.x + (accA[ct][1]+uv.y)*xa.y
            + (accA[ct][2]+uv.z)*xa.z + (accA[ct][3]+uv.w)*xa.w;
      dotB += (accB[ct][0]+uv.x)*xb.x + (accB[ct][1]+uv.y)*xb.y
            + (accB[ct][2]+uv.z)*xb.z + (accB[ct][3]+uv.w)*xb.w;
    }
    dotA += __shfl_xor(dotA, 16); dotA += __shfl_xor(dotA, 32);
    dotB += __shfl_xor(dotB, 16); dotB += __shfl_xor(dotB, 32);
    double esum = 0.0;
    if (g == 0){
      float b0v = b0[y];
      if (rA < N){
        float lv = 0.08838834764831843f * (dotA + b0v);
        lo_out[(u64)y*N + rA] = lv; esum += (double)expf(lv);
      }
      if (rB < N){
        float lv = 0.08838834764831843f * (dotB + b0v);
        lo_out[(u64)y*N + rB] = lv; esum += (double)expf(lv);
      }
    }
#pragma unroll
    for (int o=1;o<64;o<<=1) esum += __shfl_xor(esum, o);
    if (lane == 0) zsh[w] = esum;

    saccA += __shfl_xor(saccA, 16); saccA += __shfl_xor(saccA, 32);
    saccB += __shfl_xor(saccB, 16); saccB += __shfl_xor(saccB, 32);
    if (g == 0){
      double cc0 = c0[y];
      if (rA < N) s[(u64)y*N + rA] = saccA + cc0;
      if (rB < N) s[(u64)y*N + rB] = saccB + cc0;
    }
  }
  __syncthreads();                           // phase-1 LDS reads done; zsh visible

  // ---- stage Wv-hi; write zpart ----
  {
    const uint4* gh = (const uint4*)(WvH + (u64)y*16384);
    uint4* la = (uint4*)shW;
#pragma unroll
    for (int i=0;i<8;++i) la[t + i*256] = gh[t + i*256];
  }
  if (t == 0) zpart[(u64)y*gridDim.x + blockIdx.x] = zsh[0]+zsh[1]+zsh[2]+zsh[3];
  __syncthreads();

  // ---- phase 2a: v-GEMM hi products ----
#pragma unroll
  for (int i=0;i<8;++i){
#pragma unroll
    for (int j=0;j<4;++j){ accA[i][j] = 0.f; accB[i][j] = 0.f; }
  }
#pragma unroll
  for (int ks=0; ks<4; ++ks){
#pragma unroll
    for (int ct=0; ct<8; ++ct){
      bf16x8 wh = WF[(ct*4 + ks)*64 + lane];
      accA[ct] = __builtin_amdgcn_mfma_f32_16x16x32_bf16(wh, fAh[ks], accA[ct], 0, 0, 0);
      accA[ct] = __builtin_amdgcn_mfma_f32_16x16x32_bf16(wh, fAl[ks], accA[ct], 0, 0, 0);
      accB[ct] = __builtin_amdgcn_mfma_f32_16x16x32_bf16(wh, fBh[ks], accB[ct], 0, 0, 0);
      accB[ct] = __builtin_amdgcn_mfma_f32_16x16x32_bf16(wh, fBl[ks], accB[ct], 0, 0, 0);
    }
  }

  // ---- phase 2b (f32-v only): Wv-lo x hi-fragments ----
  if (!VBF16){
    __syncthreads();
    {
      const uint4* gl = (const uint4*)(WvL + (u64)y*16384);
      uint4* la = (uint4*)shW;
#pragma unroll
      for (int i=0;i<8;++i) la[t + i*256] = gl[t + i*256];
    }
    __syncthreads();
#pragma unroll
    for (int ks=0; ks<4; ++ks){
#pragma unroll
      for (int ct=0; ct<8; ++ct){
        bf16x8 wl = WF[(ct*4 + ks)*64 + lane];
        accA[ct] = __builtin_amdgcn_mfma_f32_16x16x32_bf16(wl, fAh[ks], accA[ct], 0, 0, 0);
        accB[ct] = __builtin_amdgcn_mfma_f32_16x16x32_bf16(wl, fBh[ks], accB[ct], 0, 0, 0);
      }
    }
  }

  if (VBF16){
    unsigned short* outp = (unsigned short*)vout + (u64)y*N*D;
#pragma unroll
    for (int ct=0; ct<8; ++ct){
      float4 bv = ((const float4*)bvsh)[ct*4 + g];
      if (rA < N){
        ushort4 o;
        o.x = f2bf(accA[ct][0]+bv.x); o.y = f2bf(accA[ct][1]+bv.y);
        o.z = f2bf(accA[ct][2]+bv.z); o.w = f2bf(accA[ct][3]+bv.w);
        *(ushort4*)(outp + (u64)rA*D + ct*16 + g*4) = o;
      }
      if (rB < N){
        ushort4 o;
        o.x = f2bf(accB[ct][0]+bv.x); o.y = f2bf(accB[ct][1]+bv.y);
        o.z = f2bf(accB[ct][2]+bv.z); o.w = f2bf(accB[ct][3]+bv.w);
        *(ushort4*)(outp + (u64)rB*D + ct*16 + g*4) = o;
      }
    }
  } else {
    float* outp = (float*)vout + (u64)y*N*D;
#pragma unroll
    for (int ct=0; ct<8; ++ct){
      float4 bv = ((const float4*)bvsh)[ct*4 + g];
      if (rA < N){
        float4 o = make_float4(accA[ct][0]+bv.x, accA[ct][1]+bv.y, accA[ct][2]+bv.z, accA[ct][3]+bv.w);
        *(float4*)(outp + (u64)rA*D + ct*16 + g*4) = o;
      }
      if (rB < N){
        float4 o = make_float4(accB[ct][0]+bv.x, accB[ct][1]+bv.y, accB[ct][2]+bv.z, accB[ct][3]+bv.w);
        *(float4*)(outp + (u64)rB*D + ct*16 + g*4) = o;
      }
    }
  }
}

// ---------------- aggregation: 16 nodes per block (2 per 32-lane half) ----------------
// WX: write next-layer xsum partials. FUSE (L1): block does 16-row self-residual GEMM, writes FINAL f32.
// out stores are NON-TEMPORAL (not re-read soon; preserves L3 for the v-gather working set).

template<int VBF16, int WX, int FUSE>
__global__ __launch_bounds__(256) void k_agg(const int* __restrict__ off, const int* __restrict__ csr,
                                             const double* __restrict__ s, const void* __restrict__ vv_,
                                             const float* __restrict__ l, const double* __restrict__ Z,
                                             float* __restrict__ out, float* __restrict__ xpart,
                                             const unsigned short* __restrict__ fuseW,
                                             const float* __restrict__ fuseB, int N, int E){
  __shared__ float shx[WX ? 1024 : 1];
  __shared__ unsigned short fh[FUSE?4:1][FUSE?64:1][8];
  __shared__ unsigned short fl[FUSE?4:1][FUSE?64:1][8];

  int t = threadIdx.x;
  int sl = t & 31;
  int hw = t >> 5;                           // 8 half-waves
  int hb = t & 32;
  int y = blockIdx.y;
  const int* offp = off + (u64)y*(N+1);
  const int* csrp = csr + (u64)y*E;
  const double* sp = s + (u64)(1-y)*N;       // logits live on src type = other type
  const float Zy = (float)Z[y];

  float4 xacc = make_float4(0.f,0.f,0.f,0.f);

  for (int nn = 0; nn < 2; ++nn){
    int n = blockIdx.x*16 + hw*2 + nn;
    if (n < N){
      int beg = offp[n], end = offp[n+1];
      int dg = end - beg;
      float ax=0.f, ay=0.f, az=0.f, aw=0.f;
      if (dg > 0){
        if (dg <= 32){
          bool act = sl < dg;
          int idx = csrp[beg + (act ? sl : 0)];
          double sv = act ? sp[idx] : -1e300;
          double m = sv;
#pragma unroll
          for (int o=16;o;o>>=1){ double u = __shfl_xor(m, o); m = u > m ? u : m; }
          float e = act ? expf((float)(sv - m)) : 0.f;
          float Zl = e;
#pragma unroll
          for (int o=16;o;o>>=1) Zl += __shfl_xor(Zl, o);
          float wgt = e / (Zl * (float)dg);
          for (int k=0;k<dg;++k){
            float wk = __shfl(wgt, hb + k);
            int sk = __shfl(idx, hb + k);
            if (VBF16){
              const unsigned short* vsrc = (const unsigned short*)vv_ + (u64)(1-y)*N*D;
              ushort4 vv = *(const ushort4*)(vsrc + (u64)sk*D + sl*4);
              ax = fmaf(wk, bf2f(vv.x), ax); ay = fmaf(wk, bf2f(vv.y), ay);
              az = fmaf(wk, bf2f(vv.z), az); aw = fmaf(wk, bf2f(vv.w), aw);
            } else {
              const float* vsrc = (const float*)vv_ + (u64)(1-y)*N*D;
              float4 vv = *(const float4*)(vsrc + (u64)sk*D + sl*4);
              ax = fmaf(wk, vv.x, ax); ay = fmaf(wk, vv.y, ay);
              az = fmaf(wk, vv.z, az); aw = fmaf(wk, vv.w, aw);
            }
          }
        } else {
          double m = -1e300;
          for (int e2=beg;e2<end;++e2){ double sv = sp[csrp[e2]]; m = sv > m ? sv : m; }
          float Zl = 0.f;
          for (int e2=beg;e2<end;++e2) Zl += expf((float)(sp[csrp[e2]] - m));
          float inv = 1.f / (Zl * (float)dg);
          for (int e2=beg;e2<end;++e2){
            int sk = csrp[e2];
            float wk = expf((float)(sp[sk] - m)) * inv;
            if (VBF16){
              const unsigned short* vsrc = (const unsigned short*)vv_ + (u64)(1-y)*N*D;
              ushort4 vv = *(const ushort4*)(vsrc + (u64)sk*D + sl*4);
              ax = fmaf(wk, bf2f(vv.x), ax); ay = fmaf(wk, bf2f(vv.y), ay);
              az = fmaf(wk, bf2f(vv.z), az); aw = fmaf(wk, bf2f(vv.w), aw);
            } else {
              const float* vsrc = (const float*)vv_ + (u64)(1-y)*N*D;
              float4 vv = *(const float4*)(vsrc + (u64)sk*D + sl*4);
              ax = fmaf(wk, vv.x, ax); ay = fmaf(wk, vv.y, ay);
              az = fmaf(wk, vv.z, az); aw = fmaf(wk, vv.w, aw);
            }
          }
        }
      }
      float a = expf(l[(u64)y*N + n]) / Zy;
      if (VBF16){
        const unsigned short* vself = (const unsigned short*)vv_ + (u64)y*N*D;
        ushort4 vs = *(const ushort4*)(vself + (u64)n*D + sl*4);
        ax = fmaf(a, bf2f(vs.x), ax); ay = fmaf(a, bf2f(vs.y), ay);
        az = fmaf(a, bf2f(vs.z), az); aw = fmaf(a, bf2f(vs.w), aw);
      } else {
        const float* vself = (const float*)vv_ + (u64)y*N*D;
        float4 vs = *(const float4*)(vself + (u64)n*D + sl*4);
        ax = fmaf(a, vs.x, ax); ay = fmaf(a, vs.y, ay);
        az = fmaf(a, vs.z, az); aw = fmaf(a, vs.w, aw);
      }
      if (FUSE){
        // write row (slot r) into MFMA B-fragment tables, bf16 hi/lo
        int r = hw*2 + nn;
        int ks = sl >> 3, g2 = (sl >> 1) & 3, j0 = (sl & 1)*4;
        ushort4 h, lo4;
        h.x = f2bf(ax); h.y = f2bf(ay); h.z = f2bf(az); h.w = f2bf(aw);
        lo4.x = f2bf(ax - bf2f(h.x)); lo4.y = f2bf(ay - bf2f(h.y));
        lo4.z = f2bf(az - bf2f(h.z)); lo4.w = f2bf(aw - bf2f(h.w));
        *(ushort4*)&fh[ks][r + 16*g2][j0] = h;
        *(ushort4*)&fl[ks][r + 16*g2][j0] = lo4;
      } else {
        f32x4 o4; o4[0]=ax; o4[1]=ay; o4[2]=az; o4[3]=aw;
        __builtin_nontemporal_store(o4, (f32x4*)(out + (u64)y*N*D + (u64)n*D + sl*4));
        if (WX){
          float df = (float)dg;
          xacc.x = fmaf(df, ax, xacc.x); xacc.y = fmaf(df, ay, xacc.y);
          xacc.z = fmaf(df, az, xacc.z); xacc.w = fmaf(df, aw, xacc.w);
        }
      }
    }
  }
  if (WX){
    __syncthreads();
    *(float4*)(shx + hw*128 + sl*4) = xacc;
    __syncthreads();
    if (t < 128){
      float ssum = 0.f;
#pragma unroll
      for (int i=0;i<8;++i) ssum += shx[i*128 + t];
      xpart[((u64)y*gridDim.x + blockIdx.x)*128 + t] = ssum;
    }
  }
  if (FUSE){
    __syncthreads();
    // 16-row self-residual GEMM: final = gathered @ Wself (2-prod) + b + gathered
    const unsigned short* SHp = fuseW + (u64)y*16384;
    const float* bsp = fuseB + y*D;
    float* outp = out + (u64)y*N*D;
    int wv = t >> 6, lane = t & 63;
    int rloc = lane & 15, gq = lane >> 4;
    int n2 = blockIdx.x*16 + rloc;
#pragma unroll
    for (int cc2=0; cc2<2; ++cc2){
      int ct = wv*2 + cc2;
      f32x4 acc;
      acc[0]=0.f; acc[1]=0.f; acc[2]=0.f; acc[3]=0.f;
#pragma unroll
      for (int ks=0; ks<4; ++ks){
        bf16x8 wh = *(const bf16x8*)(SHp + ((u64)(ct*4+ks)*64 + lane)*8);
        bf16x8 xh = *(const bf16x8*)&fh[ks][lane][0];
        bf16x8 xl = *(const bf16x8*)&fl[ks][lane][0];
        acc = __builtin_amdgcn_mfma_f32_16x16x32_bf16(wh, xh, acc, 0, 0, 0);
        acc = __builtin_amdgcn_mfma_f32_16x16x32_bf16(wh, xl, acc, 0, 0, 0);
      }
      if (n2 < N){
        int col0 = ct*16 + gq*4;
        int ks2 = col0 >> 5, g22 = (col0 >> 3) & 3, j02 = col0 & 7;
        ushort4 rh = *(const ushort4*)&fh[ks2][rloc + 16*g22][j02];
        ushort4 rl = *(const ushort4*)&fl[ks2][rloc + 16*g22][j02];
        float4 bv = *(const float4*)(bsp + col0);
        f32x4 o4;
        o4[0] = acc[0] + bv.x + bf2f(rh.x) + bf2f(rl.x);
        o4[1] = acc[1] + bv.y + bf2f(rh.y) + bf2f(rl.y);
        o4[2] = acc[2] + bv.z + bf2f(rh.z) + bf2f(rl.z);
        o4[3] = acc[3] + bv.w + bf2f(rh.w) + bf2f(rl.w);
        __builtin_nontemporal_store(o4, (f32x4*)(outp + (u64)n2*D + col0));
      }
    }
  }
}

// ---------------- launch ----------------

extern "C" void kernel_launch(void* const* d_in, const int* in_sizes, int n_in,
                              void* d_out, int out_size, void* d_ws, size_t ws_size,
                              hipStream_t stream){
  const float* x_user = (const float*)d_in[0];
  const float* x_item = (const float*)d_in[1];
  const int*   ei_u2i = (const int*)d_in[2];   // [2,E]: row0 src(user), row1 dst(item)
  const int*   ei_i2u = (const int*)d_in[3];   // [2,E]: row0 src(item), row1 dst(user)
  const float* qkv_w  = (const float*)d_in[4]; // [2,2,3,D,D]
  const float* qkv_b  = (const float*)d_in[5]; // [2,2,3,D]
  const float* rel_w  = (const float*)d_in[6]; // [2,2,D,D]
  const float* self_w = (const float*)d_in[7]; // [2,D,D]
  const float* self_b = (const float*)d_in[8]; // [2,D]

  const int N = in_sizes[0] / D;
  const int E = in_sizes[2] / 2;
  float* outU = (float*)d_out;                 // [2][N][D] contiguous (user then item)

  const int nblk = (N + 127)/128;
  const int RPB  = 160;
  const int NB0  = (N + RPB - 1)/RPB;
  const int gAgg = (N + 15)/16;
  const int nsb  = (N + SCB - 1)/SCB;
  const int maxPart = (gAgg > NB0 ? gAgg : NB0);

  char* p = (char*)d_ws;
  auto alloc = [&](size_t bytes)->char*{ char* r = p; p += (bytes + 255)/256*256; return r; };
  float*  v    = (float*) alloc((u64)2*N*D*4);           // f32 for L=0; aliased bf16 for L=1
  double* s    = (double*)alloc((u64)2*N*8);
  float*  l    = (float*) alloc((u64)2*N*4);
  int*    deg  = (int*)   alloc((u64)2*N*4);
  int*    off  = (int*)   alloc((u64)2*(N+1)*4);
  int*    cur  = (int*)   alloc((u64)2*N*4);
  int*    csr  = (int*)   alloc((u64)2*E*4);
  unsigned short* WvH = (unsigned short*)alloc(2*16384*2);
  unsigned short* WvL = (unsigned short*)alloc(2*16384*2);
  unsigned short* MH  = (unsigned short*)alloc(2*16384*2);
  unsigned short* SH  = (unsigned short*)alloc(2*16384*2);
  unsigned short* SL  = (unsigned short*)alloc(2*16384*2);
  float*  u1   = (float*) alloc(2*D*4);
  float*  b0   = (float*) alloc(256);
  double* zpart= (double*)alloc((u64)2*nblk*8);
  float*  xpart= (float*) alloc((u64)2*maxPart*128*4);
  double* xpd  = (double*)alloc((u64)2*32*128*8);
  double* Z    = (double*)alloc(256);
  double* c    = (double*)alloc(2*128*8);
  double* c0   = (double*)alloc(256);
  int*    bsum = (int*)   alloc((u64)2*nsb*4);

  const int gE = (E + 255)/256;

  // ---- graph prep (layer-invariant): y=0 -> dst=user (ei_i2u), y=1 -> dst=item (ei_u2i)
  hipMemsetAsync(deg, 0, (u64)2*N*4, stream);
  k_hist<<<dim3(gE,2),256,0,stream>>>(ei_i2u + E, ei_u2i + E, deg, N, E);
  k_scanA<<<dim3(nsb,2),256,0,stream>>>(deg, bsum, N, nsb);
  k_scanC<<<dim3(nsb,2),256,0,stream>>>(deg, bsum, off, cur, N, nsb, E);
  k_fill<<<dim3(gE,2),256,0,stream>>>(ei_i2u, ei_u2i, cur, csr, N, E);
  k_pack<<<dim3(64,2),256,0,stream>>>(self_w, D*D, SH, SL);

  // ---- layer-0 xsum from initial features
  k_xsum0<<<dim3(NB0,2),256,0,stream>>>(x_user, x_item, deg, xpart, N, RPB);
  k_redA<<<dim3(32,2),256,0,stream>>>(xpart, xpd, NB0);

  for (int L=0; L<2; ++L){
    const float* xu = L ? outU : x_user;
    const float* xi = L ? (outU + (u64)N*D) : x_item;
    k_prep<<<386,256,0,stream>>>(xpd, qkv_w, qkv_b, rel_w, L, E, c, c0, MH, u1, b0, WvH, WvL);
    if (L == 0){
      k_mfqv<0><<<dim3(nblk,2),256,0,stream>>>(xu, xi, MH, WvH, WvL, qkv_b + (u64)(L*6+2)*D, 3*D,
                                               u1, b0, c, c0, (void*)v, l, zpart, s, N);
      k_zred<<<2,256,0,stream>>>(zpart, Z, nblk);
      k_agg<0,1,0><<<dim3(gAgg,2),256,0,stream>>>(off, csr, s, (const void*)v, l, Z,
                                                  outU, xpart, nullptr, nullptr, N, E);
      k_redA<<<dim3(32,2),256,0,stream>>>(xpart, xpd, gAgg);
    } else {
      k_mfqv<1><<<dim3(nblk,2),256,0,stream>>>(xu, xi, MH, WvH, WvL, qkv_b + (u64)(L*6+2)*D, 3*D,
                                               u1, b0, c, c0, (void*)v, l, zpart, s, N);
      k_zred<<<2,256,0,stream>>>(zpart, Z, nblk);
      k_agg<1,0,1><<<dim3(gAgg,2),256,0,stream>>>(off, csr, s, (const void*)v, l, Z,
                                                  outU, xpart, SH, self_b, N, E);
    }
  }
}

// Round 14
// 672.763 us; speedup vs baseline: 1.1402x; 1.0118x over previous
//
#include <hip/hip_runtime.h>

#define D 128
typedef unsigned long long u64;
typedef __attribute__((ext_vector_type(8))) short bf16x8;
typedef __attribute__((ext_vector_type(4))) float f32x4;

__device__ __forceinline__ unsigned short f2bf(float f){   // round-to-nearest-even
  unsigned int u = __float_as_uint(f);
  return (unsigned short)((u + 0x7FFFu + ((u >> 16) & 1u)) >> 16);
}
__device__ __forceinline__ float bf2f(unsigned short h){
  return __uint_as_float(((unsigned int)h) << 16);
}
// round-nearest split: hi = rn16(f), lo = rn16(f - hi)  -> |f - hi - lo| ~ 2^-18 |f|
__device__ __forceinline__ void cvt8(float4 a0, float4 a1, bf16x8 &hi, bf16x8 &lo){
  float f[8] = {a0.x,a0.y,a0.z,a0.w,a1.x,a1.y,a1.z,a1.w};
#pragma unroll
  for (int j=0;j<8;++j){
    unsigned short h = f2bf(f[j]);
    hi[j] = (short)h;
    lo[j] = (short)f2bf(f[j] - bf2f(h));
  }
}

// ---------------- graph prep ----------------

__global__ __launch_bounds__(256) void k_hist(const int* __restrict__ dstA, const int* __restrict__ dstB,
                                              int* __restrict__ deg, int N, int E){
  int e = blockIdx.x*256 + threadIdx.x;
  int y = blockIdx.y;
  const int* d = y ? dstB : dstA;
  if (e < E) atomicAdd(&deg[(u64)y*N + d[e]], 1);
}

#define SCB 4096
__global__ __launch_bounds__(256) void k_scanA(const int* __restrict__ deg, int* __restrict__ bsum,
                                               int n, int nsb){
  int y = blockIdx.y, b = blockIdx.x;
  const int* d = deg + (u64)y*n;
  int i0 = b*SCB, i1 = i0 + SCB; if (i1 > n) i1 = n;
  int t = threadIdx.x;
  int a = 0;
  for (int i = i0 + t; i < i1; i += 256) a += d[i];
#pragma unroll
  for (int o=32;o;o>>=1) a += __shfl_xor(a, o);
  __shared__ int sh[4];
  if ((t & 63) == 0) sh[t >> 6] = a;
  __syncthreads();
  if (t == 0) bsum[y*nsb + b] = sh[0]+sh[1]+sh[2]+sh[3];
}

__global__ __launch_bounds__(256) void k_scanC(const int* __restrict__ deg, const int* __restrict__ bsum,
                                               int* __restrict__ off, int* __restrict__ cur,
                                               int n, int nsb, int E){
  int y = blockIdx.y, b = blockIdx.x;
  const int* d = deg + (u64)y*n;
  int* offp = off + (u64)y*(n+1);
  int* curp = cur + (u64)y*n;
  int t = threadIdx.x, lane = t & 63, wid = t >> 6;
  __shared__ int base_sh;
  __shared__ int wsum[4];
  if (t == 0){
    int base = 0;
    for (int i=0;i<b;++i) base += bsum[y*nsb + i];
    base_sh = base;
    if (b == 0) offp[n] = E;               // total degree == E exactly
  }
  __syncthreads();
  int idx = b*SCB + t*16;
  int v[16]; int tsum = 0;
#pragma unroll
  for (int j=0;j<16;++j){
    int ii = idx + j;
    v[j] = (ii < n) ? d[ii] : 0;
    tsum += v[j];
  }
  int sc = tsum;                           // inclusive wave scan
#pragma unroll
  for (int o=1;o<64;o<<=1){ int u = __shfl_up(sc, o); if (lane >= o) sc += u; }
  if (lane == 63) wsum[wid] = sc;
  __syncthreads();
  int wbase = 0;
  for (int i=0;i<wid;++i) wbase += wsum[i];
  int run = base_sh + wbase + sc - tsum;
#pragma unroll
  for (int j=0;j<16;++j){
    int ii = idx + j;
    if (ii < n){ offp[ii] = run; curp[ii] = run; run += v[j]; }
  }
}

__global__ __launch_bounds__(256) void k_fill(const int* __restrict__ eiA, const int* __restrict__ eiB,
                                              int* __restrict__ cur, int* __restrict__ csr, int N, int E){
  int e = blockIdx.x*256 + threadIdx.x;
  int y = blockIdx.y;
  const int* ei = y ? eiB : eiA;
  if (e < E){
    int p = atomicAdd(&cur[(u64)y*N + ei[E + e]], 1);
    csr[(u64)y*E + p] = ei[e];
  }
}

// ---------------- xsum for layer 0 (deg-weighted column sums of initial x) ----------------

__global__ __launch_bounds__(256) void k_xsum0(const float* __restrict__ x0, const float* __restrict__ x1,
                                               const int* __restrict__ deg, float* __restrict__ xpart,
                                               int N, int RPB){
  int y = blockIdx.y;
  const float* x = y ? x1 : x0;
  const int* dg = deg + (u64)y*N;
  int sub = threadIdx.x >> 5, sl = threadIdx.x & 31;
  int r0 = blockIdx.x*RPB;
  int r1 = r0 + RPB; if (r1 > N) r1 = N;
  float4 a = make_float4(0.f,0.f,0.f,0.f);
  for (int r = r0 + sub; r < r1; r += 8){
    float d = (float)dg[r];
    if (d != 0.f){
      float4 xv = *(const float4*)(x + (u64)r*D + sl*4);
      a.x = fmaf(d, xv.x, a.x); a.y = fmaf(d, xv.y, a.y);
      a.z = fmaf(d, xv.z, a.z); a.w = fmaf(d, xv.w, a.w);
    }
  }
  __shared__ float sh[1024];
  *(float4*)(sh + sub*128 + sl*4) = a;
  __syncthreads();
  if (threadIdx.x < 128){
    float s = 0.f;
#pragma unroll
    for (int i=0;i<8;++i) s += sh[i*128 + threadIdx.x];
    xpart[((u64)y*gridDim.x + blockIdx.x)*128 + threadIdx.x] = s;
  }
}

// ---- stage A: coalesced f32 partials -> 32 f64 partial rows per type ----
__global__ __launch_bounds__(256) void k_redA(const float* __restrict__ xpart, double* __restrict__ xpd, int nblk){
  int y = blockIdx.y, b = blockIdx.x;        // grid (32, 2)
  int chunk = (nblk + 31)/32;
  int r0 = b*chunk, r1 = r0 + chunk; if (r1 > nblk) r1 = nblk;
  int col = threadIdx.x & 127, half = threadIdx.x >> 7;
  double acc = 0.0;
  for (int r = r0 + half; r < r1; r += 2)
    acc += (double)xpart[((u64)y*nblk + r)*128 + col];
  __shared__ double sh[256];
  sh[threadIdx.x] = acc;
  __syncthreads();
  if (half == 0) xpd[((u64)y*32 + b)*128 + col] = acc + sh[col + 128];
}

__global__ __launch_bounds__(256) void k_zred(const double* __restrict__ zpart, double* __restrict__ Z, int nblk){
  int y = blockIdx.x;
  double z = 0.0;
  for (int i = threadIdx.x; i < nblk; i += 256) z += zpart[(u64)y*nblk + i];
#pragma unroll
  for (int o=32;o;o>>=1) z += __shfl_xor(z, o);
  __shared__ double sh[4];
  if ((threadIdx.x & 63) == 0) sh[threadIdx.x >> 6] = z;
  __syncthreads();
  if (threadIdx.x == 0) Z[y] = sh[0]+sh[1]+sh[2]+sh[3];
}

// ---------------- weight packing (bf16 hi/lo split, MFMA-fragment order) ----------------
// fragment halfword index o for (k,col): ct=col>>4, ks=k>>5, lane=(col&15)|(((k>>3)&3)<<4), j=k&7

__global__ __launch_bounds__(256) void k_pack(const float* __restrict__ W0, int wstride,
                                              unsigned short* __restrict__ ph, unsigned short* __restrict__ pl){
  int o = blockIdx.x*256 + threadIdx.x;      // 0..16383
  int y = blockIdx.y;
  int j = o & 7, lane = (o>>3) & 63, ks = (o>>9) & 3, ct = o >> 11;
  int k = ks*32 + ((lane>>4)<<3) + j;
  int col = (ct<<4) + (lane&15);
  float wv = W0[(u64)y*wstride + k*128 + col];
  unsigned short h = f2bf(wv);
  ph[(u64)y*16384 + o] = h;
  pl[(u64)y*16384 + o] = f2bf(wv - bf2f(h));
}

// ---------------- merged per-layer prep: coef (blocks 0-1) | prepM (2-257) | pack Wv (258-385) ----------------

__global__ __launch_bounds__(256) void k_prep(const double* __restrict__ xpd, const float* __restrict__ qkv_w,
                                              const float* __restrict__ qkv_b, const float* __restrict__ rel_w,
                                              int L, int E, double* __restrict__ c, double* __restrict__ c0,
                                              unsigned short* __restrict__ MH, float* __restrict__ u1,
                                              float* __restrict__ b0, unsigned short* __restrict__ WvH,
                                              unsigned short* __restrict__ WvL){
  __shared__ double sh[128];
  __shared__ double xs[128];
  __shared__ float qrow[128];
  int b = blockIdx.x, t = threadIdx.x;
  if (b < 2){
    // ---- coef for src type tt (f64 logit chain) ----
    int tt = b;
    const float* Wk = qkv_w + (u64)((L*2 + (1-tt))*3 + 1)*D*D;
    const float* bk = qkv_b + (u64)((L*2 + (1-tt))*3 + 1)*D;
    const float* Wq = qkv_w + (u64)((L*2 + tt)*3 + 0)*D*D;
    const float* bq = qkv_b + (u64)((L*2 + tt)*3 + 0)*D;
    const float* rel = rel_w + (u64)(L*2 + tt)*D*D;
    const double* xp = xpd + (u64)(1-tt)*32*128;
    int j = t;
    if (j < 128){
      double a = 0.0;
      for (int b2=0;b2<32;++b2) a += xp[b2*128 + j];
      xs[j] = a;
    }
    __syncthreads();
    double ks = 0.0;
    if (j < 128){
      ks = (double)E * (double)bk[j];
      for (int d=0; d<128; ++d) ks += xs[d] * (double)Wk[d*128+j];
      sh[j] = ks;
    }
    __syncthreads();
    double tmp = 0.0;
    if (j < 128){
      for (int cc=0; cc<128; ++cc) tmp += (double)rel[j*128+cc] * sh[cc];
    }
    __syncthreads();
    if (j < 128) sh[j] = tmp;
    __syncthreads();
    if (j < 128){
      const double scale = 0.08838834764831843;  // 1/sqrt(128)
      double cv = 0.0;
      for (int k2=0;k2<128;++k2) cv += (double)Wq[j*128+k2] * sh[k2];
      c[tt*128 + j] = cv * scale;
      if (j == 0){
        double z = 0.0;
        for (int k2=0;k2<128;++k2) z += (double)bq[k2] * sh[k2];
        c0[tt] = z * scale;
      }
    }
  } else if (b < 258){
    // ---- prepM: M[a][:] for (y, a) ----
    int idx = b - 2;
    int y = idx >> 7, a = idx & 127;
    const float* Wq = qkv_w + (u64)((L*2 + y)*3 + 0)*D*D;
    const float* Wk = qkv_w + (u64)((L*2 + y)*3 + 1)*D*D;
    const float* bq = qkv_b + (u64)((L*2 + y)*3 + 0)*D;
    const float* bk = qkv_b + (u64)((L*2 + y)*3 + 1)*D;
    if (t < 128) qrow[t] = Wq[a*128+t];
    __syncthreads();
    if (t < 128){
      int bcol = t;
      const float* krow = Wk + bcol*128;
      float acc = 0.f;
      for (int j=0;j<128;++j) acc += qrow[j]*krow[j];
      int o = (bcol>>4)*2048 + (a>>5)*512 + (((bcol&15)|(((a>>3)&3)<<4)))*8 + (a&7);
      MH[(u64)y*16384 + o] = f2bf(acc);
      if (bcol == 0){
        float s1 = 0.f;
        for (int j=0;j<128;++j) s1 += Wq[a*128+j]*bk[j] + Wk[a*128+j]*bq[j];
        u1[y*D + a] = s1;
        if (a == 0){
          float z = 0.f;
          for (int j=0;j<128;++j) z += bq[j]*bk[j];
          b0[y] = z;
        }
      }
    }
  } else {
    // ---- pack Wv (both types) ----
    int lin = (b - 258)*256 + t;               // 0..32767
    int y = lin >> 14, o = lin & 16383;
    int j = o & 7, lane = (o>>3) & 63, ks = (o>>9) & 3, ct = o >> 11;
    int k = ks*32 + ((lane>>4)<<3) + j;
    int col = (ct<<4) + (lane&15);
    float wv = qkv_w[(u64)((L*2 + y)*3 + 2)*D*D + k*128 + col];
    unsigned short h = f2bf(wv);
    WvH[(u64)y*16384 + o] = h;
    WvL[(u64)y*16384 + o] = f2bf(wv - bf2f(h));
  }
}

// ---------------- fused quadform + v-projection MFMA kernel (single 32 KB staging buffer) ----------------

template<int VBF16>
__global__ __launch_bounds__(256,3) void k_mfqv(
    const float* __restrict__ x0, const float* __restrict__ x1,
    const unsigned short* __restrict__ MH,
    const unsigned short* __restrict__ WvH, const unsigned short* __restrict__ WvL,
    const float* __restrict__ bias_v, int bias_stride,
    const float* __restrict__ u1, const float* __restrict__ b0,
    const double* __restrict__ c, const double* __restrict__ c0,
    void* __restrict__ vout, float* __restrict__ lo_out,
    double* __restrict__ zpart, double* __restrict__ s, int N)
{
  __shared__ unsigned short shW[16384];      // 32 KB staging: M-hi -> Wv-hi -> Wv-lo
  __shared__ double csh[128];
  __shared__ float u1sh[128];
  __shared__ float bvsh[128];
  __shared__ double zsh[4];

  int y = blockIdx.y;
  int t = threadIdx.x;
  const float* x = y ? x1 : x0;

  {
    const uint4* gm = (const uint4*)(MH + (u64)y*16384);
    uint4* la = (uint4*)shW;
#pragma unroll
    for (int i=0;i<8;++i) la[t + i*256] = gm[t + i*256];
    if (t < 128){
      csh[t] = c[y*128 + t];
      u1sh[t] = u1[y*D + t];
      bvsh[t] = bias_v[(u64)y*bias_stride + t];
    }
  }
  __syncthreads();

  int w = t >> 6, lane = t & 63;
  int g = lane >> 4, cb = lane & 15;
  int strip0 = blockIdx.x*128 + w*32;
  int rA = strip0 + cb, rB = rA + 16;
  const float* xA = x + (u64)(rA < N ? rA : N-1)*D;
  const float* xB = x + (u64)(rB < N ? rB : N-1)*D;

  f32x4 accA[8], accB[8];
#pragma unroll
  for (int i=0;i<8;++i){
#pragma unroll
    for (int j=0;j<4;++j){ accA[i][j] = 0.f; accB[i][j] = 0.f; }
  }
  double saccA = 0.0, saccB = 0.0;
  bf16x8 fAh[4], fAl[4], fBh[4], fBl[4];

  const bf16x8* WF = (const bf16x8*)shW;

  // ---- phase 1: load fragments once, sdot (f64), M-GEMM (hi-only, 2 products) ----
#pragma unroll
  for (int ks=0; ks<4; ++ks){
    float4 a0  = *(const float4*)(xA + ks*32 + g*8);
    float4 a1  = *(const float4*)(xA + ks*32 + g*8 + 4);
    float4 bb0 = *(const float4*)(xB + ks*32 + g*8);
    float4 bb1 = *(const float4*)(xB + ks*32 + g*8 + 4);
    cvt8(a0, a1, fAh[ks], fAl[ks]);
    cvt8(bb0, bb1, fBh[ks], fBl[ks]);
    {
      const double* cp = csh + ks*32 + g*8;
      saccA += (double)a0.x*cp[0] + (double)a0.y*cp[1] + (double)a0.z*cp[2] + (double)a0.w*cp[3]
             + (double)a1.x*cp[4] + (double)a1.y*cp[5] + (double)a1.z*cp[6] + (double)a1.w*cp[7];
      saccB += (double)bb0.x*cp[0] + (double)bb0.y*cp[1] + (double)bb0.z*cp[2] + (double)bb0.w*cp[3]
             + (double)bb1.x*cp[4] + (double)bb1.y*cp[5] + (double)bb1.z*cp[6] + (double)bb1.w*cp[7];
    }
#pragma unroll
    for (int ct=0; ct<8; ++ct){
      bf16x8 mh = WF[(ct*4 + ks)*64 + lane];
      accA[ct] = __builtin_amdgcn_mfma_f32_16x16x32_bf16(mh, fAh[ks], accA[ct], 0, 0, 0);
      accA[ct] = __builtin_amdgcn_mfma_f32_16x16x32_bf16(mh, fAl[ks], accA[ct], 0, 0, 0);
      accB[ct] = __builtin_amdgcn_mfma_f32_16x16x32_bf16(mh, fBh[ks], accB[ct], 0, 0, 0);
      accB[ct] = __builtin_amdgcn_mfma_f32_16x16x32_bf16(mh, fBl[ks], accB[ct], 0, 0, 0);
    }
  }

  // ---- epilogue 1: l, Z partial, s ----
  {
    float dotA = 0.f, dotB = 0.f;
#pragma unroll
    for (int ct=0; ct<8; ++ct){
      float4 uv = ((const float4*)u1sh)[ct*4 + g];
      float4 xa = *(const float4*)(xA + ct*16 + g*4);
      float4 xb = *(const float4*)(xB + ct*16 + g*4);
      dotA += (accA[ct][0]+uv.x)*xa.x + (accA[ct][1]+uv.y)*xa.y
            + (accA[ct][2]+uv.z)*xa.z + (accA[ct][3]+uv.w)*xa.w;
      dotB += (accB[ct][0]+uv.x)*xb.x + (accB[ct][1]+uv.y)*xb.y
            + (accB[ct][2]+uv.z)*xb.z + (accB[ct][3]+uv.w)*xb.w;
    }
    dotA += __shfl_xor(dotA, 16); dotA += __shfl_xor(dotA, 32);
    dotB += __shfl_xor(dotB, 16); dotB += __shfl_xor(dotB, 32);
    double esum = 0.0;
    if (g == 0){
      float b0v = b0[y];
      if (rA < N){
        float lv = 0.08838834764831843f * (dotA + b0v);
        lo_out[(u64)y*N + rA] = lv; esum += (double)expf(lv);
      }
      if (rB < N){
        float lv = 0.08838834764831843f * (dotB + b0v);
        lo_out[(u64)y*N + rB] = lv; esum += (double)expf(lv);
      }
    }
#pragma unroll
    for (int o=1;o<64;o<<=1) esum += __shfl_xor(esum, o);
    if (lane == 0) zsh[w] = esum;

    saccA += __shfl_xor(saccA, 16); saccA += __shfl_xor(saccA, 32);
    saccB += __shfl_xor(saccB, 16); saccB += __shfl_xor(saccB, 32);
    if (g == 0){
      double cc0 = c0[y];
      if (rA < N) s[(u64)y*N + rA] = saccA + cc0;
      if (rB < N) s[(u64)y*N + rB] = saccB + cc0;
    }
  }
  __syncthreads();                           // phase-1 LDS reads done; zsh visible

  // ---- stage Wv-hi; write zpart ----
  {
    const uint4* gh = (const uint4*)(WvH + (u64)y*16384);
    uint4* la = (uint4*)shW;
#pragma unroll
    for (int i=0;i<8;++i) la[t + i*256] = gh[t + i*256];
  }
  if (t == 0) zpart[(u64)y*gridDim.x + blockIdx.x] = zsh[0]+zsh[1]+zsh[2]+zsh[3];
  __syncthreads();

  // ---- phase 2a: v-GEMM hi products ----
#pragma unroll
  for (int i=0;i<8;++i){
#pragma unroll
    for (int j=0;j<4;++j){ accA[i][j] = 0.f; accB[i][j] = 0.f; }
  }
#pragma unroll
  for (int ks=0; ks<4; ++ks){
#pragma unroll
    for (int ct=0; ct<8; ++ct){
      bf16x8 wh = WF[(ct*4 + ks)*64 + lane];
      accA[ct] = __builtin_amdgcn_mfma_f32_16x16x32_bf16(wh, fAh[ks], accA[ct], 0, 0, 0);
      accA[ct] = __builtin_amdgcn_mfma_f32_16x16x32_bf16(wh, fAl[ks], accA[ct], 0, 0, 0);
      accB[ct] = __builtin_amdgcn_mfma_f32_16x16x32_bf16(wh, fBh[ks], accB[ct], 0, 0, 0);
      accB[ct] = __builtin_amdgcn_mfma_f32_16x16x32_bf16(wh, fBl[ks], accB[ct], 0, 0, 0);
    }
  }

  // ---- phase 2b (f32-v only): Wv-lo x hi-fragments ----
  if (!VBF16){
    __syncthreads();
    {
      const uint4* gl = (const uint4*)(WvL + (u64)y*16384);
      uint4* la = (uint4*)shW;
#pragma unroll
      for (int i=0;i<8;++i) la[t + i*256] = gl[t + i*256];
    }
    __syncthreads();
#pragma unroll
    for (int ks=0; ks<4; ++ks){
#pragma unroll
      for (int ct=0; ct<8; ++ct){
        bf16x8 wl = WF[(ct*4 + ks)*64 + lane];
        accA[ct] = __builtin_amdgcn_mfma_f32_16x16x32_bf16(wl, fAh[ks], accA[ct], 0, 0, 0);
        accB[ct] = __builtin_amdgcn_mfma_f32_16x16x32_bf16(wl, fBh[ks], accB[ct], 0, 0, 0);
      }
    }
  }

  if (VBF16){
    unsigned short* outp = (unsigned short*)vout + (u64)y*N*D;
#pragma unroll
    for (int ct=0; ct<8; ++ct){
      float4 bv = ((const float4*)bvsh)[ct*4 + g];
      if (rA < N){
        ushort4 o;
        o.x = f2bf(accA[ct][0]+bv.x); o.y = f2bf(accA[ct][1]+bv.y);
        o.z = f2bf(accA[ct][2]+bv.z); o.w = f2bf(accA[ct][3]+bv.w);
        *(ushort4*)(outp + (u64)rA*D + ct*16 + g*4) = o;
      }
      if (rB < N){
        ushort4 o;
        o.x = f2bf(accB[ct][0]+bv.x); o.y = f2bf(accB[ct][1]+bv.y);
        o.z = f2bf(accB[ct][2]+bv.z); o.w = f2bf(accB[ct][3]+bv.w);
        *(ushort4*)(outp + (u64)rB*D + ct*16 + g*4) = o;
      }
    }
  } else {
    float* outp = (float*)vout + (u64)y*N*D;
#pragma unroll
    for (int ct=0; ct<8; ++ct){
      float4 bv = ((const float4*)bvsh)[ct*4 + g];
      if (rA < N){
        float4 o = make_float4(accA[ct][0]+bv.x, accA[ct][1]+bv.y, accA[ct][2]+bv.z, accA[ct][3]+bv.w);
        *(float4*)(outp + (u64)rA*D + ct*16 + g*4) = o;
      }
      if (rB < N){
        float4 o = make_float4(accB[ct][0]+bv.x, accB[ct][1]+bv.y, accB[ct][2]+bv.z, accB[ct][3]+bv.w);
        *(float4*)(outp + (u64)rB*D + ct*16 + g*4) = o;
      }
    }
  }
}

// ---------------- aggregation: BPN nodes per 32-lane half (batched latency chains) ----------------
// WX: write next-layer xsum partials. FUSE (L1): block does 16-row self-residual GEMM, writes FINAL f32.
// out stores are NON-TEMPORAL.

template<int VBF16, int WX, int FUSE, int BPN>
__global__ __launch_bounds__(256) void k_agg(const int* __restrict__ off, const int* __restrict__ csr,
                                             const double* __restrict__ s, const void* __restrict__ vv_,
                                             const float* __restrict__ l, const double* __restrict__ Z,
                                             float* __restrict__ out, float* __restrict__ xpart,
                                             const unsigned short* __restrict__ fuseW,
                                             const float* __restrict__ fuseB, int N, int E){
  __shared__ float shx[WX ? 1024 : 1];
  __shared__ unsigned short fh[FUSE?4:1][FUSE?64:1][8];
  __shared__ unsigned short fl[FUSE?4:1][FUSE?64:1][8];

  int t = threadIdx.x;
  int sl = t & 31;
  int hw = t >> 5;                           // 8 half-waves
  int hb = t & 32;
  int y = blockIdx.y;
  const int* offp = off + (u64)y*(N+1);
  const int* csrp = csr + (u64)y*E;
  const double* sp = s + (u64)(1-y)*N;       // logits live on src type = other type
  const float Zy = (float)Z[y];

  int nbase = blockIdx.x*(8*BPN) + hw*BPN;

  // ---- batched header loads: BPN independent off->csr->s chains in flight ----
  int begv[BPN], dgv[BPN], idxv[BPN];
  double svv[BPN];
  float lv_[BPN];
#pragma unroll
  for (int nn=0; nn<BPN; ++nn){
    int n = nbase + nn;
    int beg = 0, dg = 0;
    if (n < N){ beg = offp[n]; dg = offp[n+1] - beg; }
    begv[nn] = beg; dgv[nn] = dg;
    idxv[nn] = (dg > 0 && dg <= 32 && sl < dg) ? csrp[beg + sl] : -1;
    lv_[nn] = (n < N) ? l[(u64)y*N + n] : 0.f;
  }
#pragma unroll
  for (int nn=0; nn<BPN; ++nn)
    svv[nn] = (idxv[nn] >= 0) ? sp[idxv[nn]] : -1e300;

  float4 xacc = make_float4(0.f,0.f,0.f,0.f);

#pragma unroll
  for (int nn = 0; nn < BPN; ++nn){
    int n = nbase + nn;
    if (n < N){
      int beg = begv[nn], dg = dgv[nn];
      float ax=0.f, ay=0.f, az=0.f, aw=0.f;
      if (dg > 0){
        if (dg <= 32){
          double sv = svv[nn];
          double m = sv;
#pragma unroll
          for (int o=16;o;o>>=1){ double u = __shfl_xor(m, o); m = u > m ? u : m; }
          float e = (sl < dg) ? expf((float)(sv - m)) : 0.f;
          float Zl = e;
#pragma unroll
          for (int o=16;o;o>>=1) Zl += __shfl_xor(Zl, o);
          float wgt = e / (Zl * (float)dg);
          for (int k=0;k<dg;++k){
            float wk = __shfl(wgt, hb + k);
            int sk = __shfl(idxv[nn], hb + k);
            if (VBF16){
              const unsigned short* vsrc = (const unsigned short*)vv_ + (u64)(1-y)*N*D;
              ushort4 vv = *(const ushort4*)(vsrc + (u64)sk*D + sl*4);
              ax = fmaf(wk, bf2f(vv.x), ax); ay = fmaf(wk, bf2f(vv.y), ay);
              az = fmaf(wk, bf2f(vv.z), az); aw = fmaf(wk, bf2f(vv.w), aw);
            } else {
              const float* vsrc = (const float*)vv_ + (u64)(1-y)*N*D;
              float4 vv = *(const float4*)(vsrc + (u64)sk*D + sl*4);
              ax = fmaf(wk, vv.x, ax); ay = fmaf(wk, vv.y, ay);
              az = fmaf(wk, vv.z, az); aw = fmaf(wk, vv.w, aw);
            }
          }
        } else {
          double m = -1e300;
          for (int e2=beg;e2<beg+dg;++e2){ double sv = sp[csrp[e2]]; m = sv > m ? sv : m; }
          float Zl = 0.f;
          for (int e2=beg;e2<beg+dg;++e2) Zl += expf((float)(sp[csrp[e2]] - m));
          float inv = 1.f / (Zl * (float)dg);
          for (int e2=beg;e2<beg+dg;++e2){
            int sk = csrp[e2];
            float wk = expf((float)(sp[sk] - m)) * inv;
            if (VBF16){
              const unsigned short* vsrc = (const unsigned short*)vv_ + (u64)(1-y)*N*D;
              ushort4 vv = *(const ushort4*)(vsrc + (u64)sk*D + sl*4);
              ax = fmaf(wk, bf2f(vv.x), ax); ay = fmaf(wk, bf2f(vv.y), ay);
              az = fmaf(wk, bf2f(vv.z), az); aw = fmaf(wk, bf2f(vv.w), aw);
            } else {
              const float* vsrc = (const float*)vv_ + (u64)(1-y)*N*D;
              float4 vv = *(const float4*)(vsrc + (u64)sk*D + sl*4);
              ax = fmaf(wk, vv.x, ax); ay = fmaf(wk, vv.y, ay);
              az = fmaf(wk, vv.z, az); aw = fmaf(wk, vv.w, aw);
            }
          }
        }
      }
      float a = expf(lv_[nn]) / Zy;
      if (VBF16){
        const unsigned short* vself = (const unsigned short*)vv_ + (u64)y*N*D;
        ushort4 vs = *(const ushort4*)(vself + (u64)n*D + sl*4);
        ax = fmaf(a, bf2f(vs.x), ax); ay = fmaf(a, bf2f(vs.y), ay);
        az = fmaf(a, bf2f(vs.z), az); aw = fmaf(a, bf2f(vs.w), aw);
      } else {
        const float* vself = (const float*)vv_ + (u64)y*N*D;
        float4 vs = *(const float4*)(vself + (u64)n*D + sl*4);
        ax = fmaf(a, vs.x, ax); ay = fmaf(a, vs.y, ay);
        az = fmaf(a, vs.z, az); aw = fmaf(a, vs.w, aw);
      }
      if (FUSE){
        // write row (slot r) into MFMA B-fragment tables, bf16 hi/lo
        int r = hw*BPN + nn;
        int ks = sl >> 3, g2 = (sl >> 1) & 3, j0 = (sl & 1)*4;
        ushort4 h, lo4;
        h.x = f2bf(ax); h.y = f2bf(ay); h.z = f2bf(az); h.w = f2bf(aw);
        lo4.x = f2bf(ax - bf2f(h.x)); lo4.y = f2bf(ay - bf2f(h.y));
        lo4.z = f2bf(az - bf2f(h.z)); lo4.w = f2bf(aw - bf2f(h.w));
        *(ushort4*)&fh[ks][r + 16*g2][j0] = h;
        *(ushort4*)&fl[ks][r + 16*g2][j0] = lo4;
      } else {
        f32x4 o4; o4[0]=ax; o4[1]=ay; o4[2]=az; o4[3]=aw;
        __builtin_nontemporal_store(o4, (f32x4*)(out + (u64)y*N*D + (u64)n*D + sl*4));
        if (WX){
          float df = (float)dg;
          xacc.x = fmaf(df, ax, xacc.x); xacc.y = fmaf(df, ay, xacc.y);
          xacc.z = fmaf(df, az, xacc.z); xacc.w = fmaf(df, aw, xacc.w);
        }
      }
    }
  }
  if (WX){
    __syncthreads();
    *(float4*)(shx + hw*128 + sl*4) = xacc;
    __syncthreads();
    if (t < 128){
      float ssum = 0.f;
#pragma unroll
      for (int i=0;i<8;++i) ssum += shx[i*128 + t];
      xpart[((u64)y*gridDim.x + blockIdx.x)*128 + t] = ssum;
    }
  }
  if (FUSE){
    __syncthreads();
    // 16-row self-residual GEMM: final = gathered @ Wself (2-prod) + b + gathered
    const unsigned short* SHp = fuseW + (u64)y*16384;
    const float* bsp = fuseB + y*D;
    float* outp = out + (u64)y*N*D;
    int wv = t >> 6, lane = t & 63;
    int rloc = lane & 15, gq = lane >> 4;
    int n2 = blockIdx.x*16 + rloc;
#pragma unroll
    for (int cc2=0; cc2<2; ++cc2){
      int ct = wv*2 + cc2;
      f32x4 acc;
      acc[0]=0.f; acc[1]=0.f; acc[2]=0.f; acc[3]=0.f;
#pragma unroll
      for (int ks=0; ks<4; ++ks){
        bf16x8 wh = *(const bf16x8*)(SHp + ((u64)(ct*4+ks)*64 + lane)*8);
        bf16x8 xh = *(const bf16x8*)&fh[ks][lane][0];
        bf16x8 xl = *(const bf16x8*)&fl[ks][lane][0];
        acc = __builtin_amdgcn_mfma_f32_16x16x32_bf16(wh, xh, acc, 0, 0, 0);
        acc = __builtin_amdgcn_mfma_f32_16x16x32_bf16(wh, xl, acc, 0, 0, 0);
      }
      if (n2 < N){
        int col0 = ct*16 + gq*4;
        int ks2 = col0 >> 5, g22 = (col0 >> 3) & 3, j02 = col0 & 7;
        ushort4 rh = *(const ushort4*)&fh[ks2][rloc + 16*g22][j02];
        ushort4 rl = *(const ushort4*)&fl[ks2][rloc + 16*g22][j02];
        float4 bv = *(const float4*)(bsp + col0);
        f32x4 o4;
        o4[0] = acc[0] + bv.x + bf2f(rh.x) + bf2f(rl.x);
        o4[1] = acc[1] + bv.y + bf2f(rh.y) + bf2f(rl.y);
        o4[2] = acc[2] + bv.z + bf2f(rh.z) + bf2f(rl.z);
        o4[3] = acc[3] + bv.w + bf2f(rh.w) + bf2f(rl.w);
        __builtin_nontemporal_store(o4, (f32x4*)(outp + (u64)n2*D + col0));
      }
    }
  }
}

// ---------------- launch ----------------

extern "C" void kernel_launch(void* const* d_in, const int* in_sizes, int n_in,
                              void* d_out, int out_size, void* d_ws, size_t ws_size,
                              hipStream_t stream){
  const float* x_user = (const float*)d_in[0];
  const float* x_item = (const float*)d_in[1];
  const int*   ei_u2i = (const int*)d_in[2];   // [2,E]: row0 src(user), row1 dst(item)
  const int*   ei_i2u = (const int*)d_in[3];   // [2,E]: row0 src(item), row1 dst(user)
  const float* qkv_w  = (const float*)d_in[4]; // [2,2,3,D,D]
  const float* qkv_b  = (const float*)d_in[5]; // [2,2,3,D]
  const float* rel_w  = (const float*)d_in[6]; // [2,2,D,D]
  const float* self_w = (const float*)d_in[7]; // [2,D,D]
  const float* self_b = (const float*)d_in[8]; // [2,D]

  const int N = in_sizes[0] / D;
  const int E = in_sizes[2] / 2;
  float* outU = (float*)d_out;                 // [2][N][D] contiguous (user then item)

  const int nblk = (N + 127)/128;
  const int RPB  = 160;
  const int NB0  = (N + RPB - 1)/RPB;
  const int gAgg0 = (N + 31)/32;               // L0: BPN=4, 32 nodes/block
  const int gAgg1 = (N + 15)/16;               // L1: BPN=2, 16 nodes/block (FUSE tile)
  const int nsb  = (N + SCB - 1)/SCB;
  const int maxPart = (gAgg0 > NB0 ? gAgg0 : NB0);

  char* p = (char*)d_ws;
  auto alloc = [&](size_t bytes)->char*{ char* r = p; p += (bytes + 255)/256*256; return r; };
  float*  v    = (float*) alloc((u64)2*N*D*4);           // f32 for L=0; aliased bf16 for L=1
  double* s    = (double*)alloc((u64)2*N*8);
  float*  l    = (float*) alloc((u64)2*N*4);
  int*    deg  = (int*)   alloc((u64)2*N*4);
  int*    off  = (int*)   alloc((u64)2*(N+1)*4);
  int*    cur  = (int*)   alloc((u64)2*N*4);
  int*    csr  = (int*)   alloc((u64)2*E*4);
  unsigned short* WvH = (unsigned short*)alloc(2*16384*2);
  unsigned short* WvL = (unsigned short*)alloc(2*16384*2);
  unsigned short* MH  = (unsigned short*)alloc(2*16384*2);
  unsigned short* SH  = (unsigned short*)alloc(2*16384*2);
  unsigned short* SL  = (unsigned short*)alloc(2*16384*2);
  float*  u1   = (float*) alloc(2*D*4);
  float*  b0   = (float*) alloc(256);
  double* zpart= (double*)alloc((u64)2*nblk*8);
  float*  xpart= (float*) alloc((u64)2*maxPart*128*4);
  double* xpd  = (double*)alloc((u64)2*32*128*8);
  double* Z    = (double*)alloc(256);
  double* c    = (double*)alloc(2*128*8);
  double* c0   = (double*)alloc(256);
  int*    bsum = (int*)   alloc((u64)2*nsb*4);

  const int gE = (E + 255)/256;

  // ---- graph prep (layer-invariant): y=0 -> dst=user (ei_i2u), y=1 -> dst=item (ei_u2i)
  hipMemsetAsync(deg, 0, (u64)2*N*4, stream);
  k_hist<<<dim3(gE,2),256,0,stream>>>(ei_i2u + E, ei_u2i + E, deg, N, E);
  k_scanA<<<dim3(nsb,2),256,0,stream>>>(deg, bsum, N, nsb);
  k_scanC<<<dim3(nsb,2),256,0,stream>>>(deg, bsum, off, cur, N, nsb, E);
  k_fill<<<dim3(gE,2),256,0,stream>>>(ei_i2u, ei_u2i, cur, csr, N, E);
  k_pack<<<dim3(64,2),256,0,stream>>>(self_w, D*D, SH, SL);

  // ---- layer-0 xsum from initial features
  k_xsum0<<<dim3(NB0,2),256,0,stream>>>(x_user, x_item, deg, xpart, N, RPB);
  k_redA<<<dim3(32,2),256,0,stream>>>(xpart, xpd, NB0);

  for (int L=0; L<2; ++L){
    const float* xu = L ? outU : x_user;
    const float* xi = L ? (outU + (u64)N*D) : x_item;
    k_prep<<<386,256,0,stream>>>(xpd, qkv_w, qkv_b, rel_w, L, E, c, c0, MH, u1, b0, WvH, WvL);
    if (L == 0){
      k_mfqv<0><<<dim3(nblk,2),256,0,stream>>>(xu, xi, MH, WvH, WvL, qkv_b + (u64)(L*6+2)*D, 3*D,
                                               u1, b0, c, c0, (void*)v, l, zpart, s, N);
      k_zred<<<2,256,0,stream>>>(zpart, Z, nblk);
      k_agg<0,1,0,4><<<dim3(gAgg0,2),256,0,stream>>>(off, csr, s, (const void*)v, l, Z,
                                                     outU, xpart, nullptr, nullptr, N, E);
      k_redA<<<dim3(32,2),256,0,stream>>>(xpart, xpd, gAgg0);
    } else {
      k_mfqv<1><<<dim3(nblk,2),256,0,stream>>>(xu, xi, MH, WvH, WvL, qkv_b + (u64)(L*6+2)*D, 3*D,
                                               u1, b0, c, c0, (void*)v, l, zpart, s, N);
      k_zred<<<2,256,0,stream>>>(zpart, Z, nblk);
      k_agg<1,0,1,2><<<dim3(gAgg1,2),256,0,stream>>>(off, csr, s, (const void*)v, l, Z,
                                                     outU, xpart, SH, self_b, N, E);
    }
  }
}